// Round 6
// baseline (632.204 us; speedup 1.0000x reference)
//
#include <hip/hip_runtime.h>
#include <math.h>

#define N_NODES 50000
#define M_PAD   50048            /* 391*128 = 782*64 */
#define N_EDGES 800000
#define EP (N_EDGES + N_NODES)
#define DIN 256
#define HEADS 4
#define HID 64
#define F1 256
#define F2 128
#define NEG_SLOPE 0.2f
#define SCAN_NBLK ((N_NODES + 255)/256)   /* 196 */

typedef short bf16x8 __attribute__((ext_vector_type(8)));
typedef float f32x4  __attribute__((ext_vector_type(4)));

static __device__ __forceinline__ float leaky(float x){ return x > 0.f ? x : NEG_SLOPE*x; }
static __device__ __forceinline__ float elu_f(float x){ return x > 0.f ? x : (__expf(x)-1.f); }
static __device__ __forceinline__ float b2f(unsigned short u){ return __uint_as_float(((unsigned)u)<<16); }
static __device__ __forceinline__ unsigned short f2b(float f){
  unsigned u = __float_as_uint(f);
  return (unsigned short)((u + 0x7fffu + ((u>>16)&1u)) >> 16);   // RNE
}

// ---------------- CSR build ----------------
__global__ __launch_bounds__(256) void k_hist(const int* __restrict__ dst, int* __restrict__ counts){
  int e = blockIdx.x*256 + threadIdx.x;
  if (e >= EP) return;
  int d = (e < N_EDGES) ? dst[e] : (e - N_EDGES);
  atomicAdd(&counts[d], 1);
}

__global__ __launch_bounds__(256) void k_scan1(const int* __restrict__ counts,
                                               int* __restrict__ exc, int* __restrict__ bsum){
  int i = blockIdx.x*256 + threadIdx.x;
  int v = (i < N_NODES) ? counts[i] : 0;
  int lane = threadIdx.x & 63, wave = threadIdx.x >> 6;
  int inc = v;
  #pragma unroll
  for (int off=1; off<64; off<<=1){
    int n = __shfl_up(inc, off);
    if (lane >= off) inc += n;
  }
  __shared__ int wsum[4];
  if (lane == 63) wsum[wave] = inc;
  __syncthreads();
  int wpre = 0;
  #pragma unroll
  for (int w=0; w<4; w++) if (w < wave) wpre += wsum[w];
  if (i < N_NODES) exc[i] = wpre + inc - v;
  if (threadIdx.x == 255) bsum[blockIdx.x] = wpre + inc;
}

__global__ __launch_bounds__(256) void k_scan2(const int* __restrict__ bsum,
                                               int* __restrict__ bpref, int* __restrict__ offsets){
  int i = threadIdx.x;
  int v = (i < SCAN_NBLK) ? bsum[i] : 0;
  int lane = threadIdx.x & 63, wave = threadIdx.x >> 6;
  int inc = v;
  #pragma unroll
  for (int off=1; off<64; off<<=1){
    int n = __shfl_up(inc, off);
    if (lane >= off) inc += n;
  }
  __shared__ int wsum[4];
  if (lane == 63) wsum[wave] = inc;
  __syncthreads();
  int wpre = 0;
  #pragma unroll
  for (int w=0; w<4; w++) if (w < wave) wpre += wsum[w];
  if (i < SCAN_NBLK) bpref[i] = wpre + inc - v;
  if (i == 255) offsets[N_NODES] = wpre + inc;
}

__global__ __launch_bounds__(256) void k_scan3(const int* __restrict__ exc, const int* __restrict__ bpref,
                                               int* __restrict__ offsets, int* __restrict__ cursor){
  int i = blockIdx.x*256 + threadIdx.x;
  if (i >= N_NODES) return;
  int o = exc[i] + bpref[blockIdx.x];
  offsets[i] = o;
  cursor[i] = o;
}

__global__ __launch_bounds__(256) void k_scatter(const int* __restrict__ src, const int* __restrict__ dst,
                          int* __restrict__ cursor, int* __restrict__ sorted_src){
  int e = blockIdx.x*256 + threadIdx.x;
  if (e >= EP) return;
  int s, d;
  if (e < N_EDGES){ s = src[e]; d = dst[e]; } else { s = d = e - N_EDGES; }
  int pos = atomicAdd(&cursor[d], 1);
  sorted_src[pos] = s;
}

// ---------------- degree-sorted permutation (counting sort, 256 bins) ----------------
__global__ __launch_bounds__(256) void k_dhist(const int* __restrict__ counts, int* __restrict__ dbin){
  int i = blockIdx.x*256 + threadIdx.x;
  if (i >= N_NODES) return;
  int b = counts[i]; if (b > 255) b = 255;
  atomicAdd(&dbin[b], 1);
}

__global__ __launch_bounds__(256) void k_dscan(const int* __restrict__ dbin, int* __restrict__ dcur){
  int i = threadIdx.x;
  int v = dbin[i];
  int lane = threadIdx.x & 63, wave = threadIdx.x >> 6;
  int inc = v;
  #pragma unroll
  for (int off=1; off<64; off<<=1){
    int n = __shfl_up(inc, off);
    if (lane >= off) inc += n;
  }
  __shared__ int wsum[4];
  if (lane == 63) wsum[wave] = inc;
  __syncthreads();
  int wpre = 0;
  #pragma unroll
  for (int w=0; w<4; w++) if (w < wave) wpre += wsum[w];
  dcur[i] = wpre + inc - v;
}

__global__ __launch_bounds__(256) void k_dscatter(const int* __restrict__ counts, int* __restrict__ dcur,
                                                  int* __restrict__ perm){
  int i = blockIdx.x*256 + threadIdx.x;
  if (i >= N_NODES) return;
  int b = counts[i]; if (b > 255) b = 255;
  int pos = atomicAdd(&dcur[b], 1);
  perm[pos] = i;
}

// ---------------- split f32 -> bf16 hi/lo ----------------
__global__ __launch_bounds__(256) void k_splitA(const float* __restrict__ X,
                         unsigned short* __restrict__ Ahi, unsigned short* __restrict__ Alo){
  int gid = blockIdx.x*256 + threadIdx.x;
  size_t base = (size_t)gid*4;
  int row = (int)(base >> 8);
  ushort4 hi, lo;
  if (row < N_NODES){
    float4 v = *(const float4*)(X + base);
    hi.x=f2b(v.x); hi.y=f2b(v.y); hi.z=f2b(v.z); hi.w=f2b(v.w);
    lo.x=f2b(v.x-b2f(hi.x)); lo.y=f2b(v.y-b2f(hi.y));
    lo.z=f2b(v.z-b2f(hi.z)); lo.w=f2b(v.w-b2f(hi.w));
  } else {
    hi = {0,0,0,0}; lo = {0,0,0,0};
  }
  *(ushort4*)(Ahi + base) = hi;
  *(ushort4*)(Alo + base) = lo;
}

__global__ __launch_bounds__(256) void k_splitWT(const float* __restrict__ W,
                          unsigned short* __restrict__ Bhi, unsigned short* __restrict__ Blo,
                          int Kd, int Nd){
  int t = blockIdx.x*256 + threadIdx.x;
  if (t >= Kd*Nd) return;
  int n = t / Kd, k = t % Kd;
  float v = W[(size_t)k*Nd + n];
  unsigned short hi = f2b(v);
  unsigned short lo = f2b(v - b2f(hi));
  Bhi[(size_t)n*Kd + k] = hi;
  Blo[(size_t)n*Kd + k] = lo;
}

// ---------------- GEMM1 (WR=1, WC=4) with fused edot1 epilogue ----------------
__global__ __launch_bounds__(256) void k_gemm1f(
    const unsigned short* __restrict__ Ahi, const unsigned short* __restrict__ Alo,
    const unsigned short* __restrict__ Bthi, const unsigned short* __restrict__ Btlo,
    const float* __restrict__ a1s, const float* __restrict__ a1d,
    unsigned short* __restrict__ Cbf, float* __restrict__ es, float* __restrict__ ed){
  const int K = 256, Nc = F1;
  int tid = threadIdx.x;
  int wave = tid>>6, lane = tid&63;
  int wc = wave;                 // head index
  int row0 = blockIdx.x*64;
  int col0 = wc*64;
  int lrow = lane&15, lk = (lane>>4)*8;
  f32x4 acc[4][4] = {};
  for (int ks=0; ks<K; ks+=32){
    bf16x8 ah[4], al[4], bh[4], bl[4];
    #pragma unroll
    for (int i=0;i<4;i++){
      size_t aoff = (size_t)(row0 + i*16 + lrow)*K + ks + lk;
      ah[i] = *(const bf16x8*)(Ahi + aoff);
      al[i] = *(const bf16x8*)(Alo + aoff);
      size_t boff = (size_t)(col0 + i*16 + lrow)*K + ks + lk;
      bh[i] = *(const bf16x8*)(Bthi + boff);
      bl[i] = *(const bf16x8*)(Btlo + boff);
    }
    #pragma unroll
    for (int i=0;i<4;i++)
      #pragma unroll
      for (int j=0;j<4;j++)
        acc[i][j] = __builtin_amdgcn_mfma_f32_16x16x32_bf16(ah[i], bh[j], acc[i][j], 0,0,0);
    #pragma unroll
    for (int i=0;i<4;i++)
      #pragma unroll
      for (int j=0;j<4;j++)
        acc[i][j] = __builtin_amdgcn_mfma_f32_16x16x32_bf16(ah[i], bl[j], acc[i][j], 0,0,0);
    #pragma unroll
    for (int i=0;i<4;i++)
      #pragma unroll
      for (int j=0;j<4;j++)
        acc[i][j] = __builtin_amdgcn_mfma_f32_16x16x32_bf16(al[i], bh[j], acc[i][j], 0,0,0);
  }
  int crow = (lane>>4)*4, ccol = lane&15;
  // C write (bf16)
  #pragma unroll
  for (int i=0;i<4;i++)
    #pragma unroll
    for (int j=0;j<4;j++)
      #pragma unroll
      for (int q=0;q<4;q++){
        int r = row0 + i*16 + crow + q;
        int c = col0 + j*16 + ccol;
        Cbf[(size_t)r*Nc + c] = f2b(acc[i][j][q]);
      }
  // fused edot: wave wc owns head wc's 64 cols entirely
  float avs[4], avd[4];
  #pragma unroll
  for (int j=0;j<4;j++){
    avs[j] = a1s[wc*64 + j*16 + ccol];
    avd[j] = a1d[wc*64 + j*16 + ccol];
  }
  #pragma unroll
  for (int i=0;i<4;i++){
    #pragma unroll
    for (int q=0;q<4;q++){
      float ps = acc[i][0][q]*avs[0] + acc[i][1][q]*avs[1] + acc[i][2][q]*avs[2] + acc[i][3][q]*avs[3];
      float pd = acc[i][0][q]*avd[0] + acc[i][1][q]*avd[1] + acc[i][2][q]*avd[2] + acc[i][3][q]*avd[3];
      #pragma unroll
      for (int off=1; off<16; off<<=1){ ps += __shfl_xor(ps,off); pd += __shfl_xor(pd,off); }
      if ((lane&15)==0){
        int r = row0 + i*16 + crow + q;
        es[(size_t)r*4 + wc] = ps;
        ed[(size_t)r*4 + wc] = pd;
      }
    }
  }
}

// ---------------- plain GEMM (for layer 2) ----------------
template<int WR, int WC>
__global__ __launch_bounds__(256) void k_gemm_bf3(
    const unsigned short* __restrict__ Ahi, const unsigned short* __restrict__ Alo,
    const unsigned short* __restrict__ Bthi, const unsigned short* __restrict__ Btlo,
    unsigned short* __restrict__ Cbf, int Nc){
  const int K = 256;
  int tid = threadIdx.x;
  int wave = tid>>6, lane = tid&63;
  int wr = wave / WC, wc = wave % WC;
  int row0 = blockIdx.x*(WR*64) + wr*64;
  int col0 = blockIdx.y*(WC*64) + wc*64;
  int lrow = lane&15, lk = (lane>>4)*8;
  f32x4 acc[4][4] = {};
  for (int ks=0; ks<K; ks+=32){
    bf16x8 ah[4], al[4], bh[4], bl[4];
    #pragma unroll
    for (int i=0;i<4;i++){
      size_t aoff = (size_t)(row0 + i*16 + lrow)*K + ks + lk;
      ah[i] = *(const bf16x8*)(Ahi + aoff);
      al[i] = *(const bf16x8*)(Alo + aoff);
      size_t boff = (size_t)(col0 + i*16 + lrow)*K + ks + lk;
      bh[i] = *(const bf16x8*)(Bthi + boff);
      bl[i] = *(const bf16x8*)(Btlo + boff);
    }
    #pragma unroll
    for (int i=0;i<4;i++)
      #pragma unroll
      for (int j=0;j<4;j++)
        acc[i][j] = __builtin_amdgcn_mfma_f32_16x16x32_bf16(ah[i], bh[j], acc[i][j], 0,0,0);
    #pragma unroll
    for (int i=0;i<4;i++)
      #pragma unroll
      for (int j=0;j<4;j++)
        acc[i][j] = __builtin_amdgcn_mfma_f32_16x16x32_bf16(ah[i], bl[j], acc[i][j], 0,0,0);
    #pragma unroll
    for (int i=0;i<4;i++)
      #pragma unroll
      for (int j=0;j<4;j++)
        acc[i][j] = __builtin_amdgcn_mfma_f32_16x16x32_bf16(al[i], bh[j], acc[i][j], 0,0,0);
  }
  int crow = (lane>>4)*4, ccol = lane&15;
  #pragma unroll
  for (int i=0;i<4;i++)
    #pragma unroll
    for (int j=0;j<4;j++)
      #pragma unroll
      for (int q=0;q<4;q++){
        int r = row0 + i*16 + crow + q;
        int c = col0 + j*16 + ccol;
        Cbf[(size_t)r*Nc + c] = f2b(acc[i][j][q]);
      }
}

// ---------------- edot2 ----------------
__global__ __launch_bounds__(256) void k_edot2(const unsigned short* __restrict__ h2bf, const float* __restrict__ a_src,
                        const float* __restrict__ a_dst, float* __restrict__ es, float* __restrict__ ed){
  int wave=threadIdx.x>>6, lane=threadIdx.x&63;
  int n = blockIdx.x*4+wave; if (n>=N_NODES) return;
  ushort2 hv = ((const ushort2*)(h2bf + (size_t)n*F2))[lane];
  float2 s2 = ((const float2*)a_src)[lane];
  float2 d2 = ((const float2*)a_dst)[lane];
  float h0=b2f(hv.x), h1=b2f(hv.y);
  float ps = h0*s2.x + h1*s2.y;
  float pd = h0*d2.x + h1*d2.y;
  #pragma unroll
  for (int m=1;m<64;m<<=1){ ps += __shfl_xor(ps,m); pd += __shfl_xor(pd,m); }
  if (lane==0){ es[n]=ps; ed[n]=pd; }
}

// ---------------- layer-1 aggregation: single-pass, degree-sorted ----------------
__global__ __launch_bounds__(256) void k_agg1(const unsigned short* __restrict__ h1bf, const float* __restrict__ es,
                       const float* __restrict__ ed, const int* __restrict__ offsets,
                       const int* __restrict__ ssrc, const int* __restrict__ perm,
                       const float* __restrict__ b1,
                       unsigned short* __restrict__ A2hi, unsigned short* __restrict__ A2lo){
  int wave = threadIdx.x>>6, lane = threadIdx.x&63;
  int idx = blockIdx.x*4 + wave;
  if (idx >= M_PAD) return;
  if (idx >= N_NODES){                       // pad rows: zero for GEMM2
    ushort4 z = {0,0,0,0};
    ((ushort4*)(A2hi + (size_t)idx*F1))[lane] = z;
    ((ushort4*)(A2lo + (size_t)idx*F1))[lane] = z;
    return;
  }
  int d = perm[idx];
  int beg = offsets[d], end = offsets[d+1];
  int deg = end - beg;
  float4 edv = *(const float4*)(ed + (size_t)d*4);
  int head = lane>>4;
  float edh = head==0?edv.x:(head==1?edv.y:(head==2?edv.z:edv.w));
  float s0=0.f,s1=0.f,s2=0.f,s3=0.f;
  float4 acc0={0,0,0,0}, acc1={0,0,0,0}, acc2={0,0,0,0}, acc3={0,0,0,0};
  int j=0;
  for (; j+4<=deg; j+=4){
    int sn0=ssrc[beg+j], sn1=ssrc[beg+j+1], sn2=ssrc[beg+j+2], sn3=ssrc[beg+j+3];
    float e0 = es[(size_t)sn0*4+head], e1 = es[(size_t)sn1*4+head];
    float e2 = es[(size_t)sn2*4+head], e3 = es[(size_t)sn3*4+head];
    ushort4 v0 = ((const ushort4*)(h1bf + (size_t)sn0*F1))[lane];
    ushort4 v1 = ((const ushort4*)(h1bf + (size_t)sn1*F1))[lane];
    ushort4 v2 = ((const ushort4*)(h1bf + (size_t)sn2*F1))[lane];
    ushort4 v3 = ((const ushort4*)(h1bf + (size_t)sn3*F1))[lane];
    float x0 = __expf(leaky(e0+edh)), x1 = __expf(leaky(e1+edh));
    float x2 = __expf(leaky(e2+edh)), x3 = __expf(leaky(e3+edh));
    s0+=x0; s1+=x1; s2+=x2; s3+=x3;
    acc0.x=fmaf(x0,b2f(v0.x),acc0.x); acc0.y=fmaf(x0,b2f(v0.y),acc0.y); acc0.z=fmaf(x0,b2f(v0.z),acc0.z); acc0.w=fmaf(x0,b2f(v0.w),acc0.w);
    acc1.x=fmaf(x1,b2f(v1.x),acc1.x); acc1.y=fmaf(x1,b2f(v1.y),acc1.y); acc1.z=fmaf(x1,b2f(v1.z),acc1.z); acc1.w=fmaf(x1,b2f(v1.w),acc1.w);
    acc2.x=fmaf(x2,b2f(v2.x),acc2.x); acc2.y=fmaf(x2,b2f(v2.y),acc2.y); acc2.z=fmaf(x2,b2f(v2.z),acc2.z); acc2.w=fmaf(x2,b2f(v2.w),acc2.w);
    acc3.x=fmaf(x3,b2f(v3.x),acc3.x); acc3.y=fmaf(x3,b2f(v3.y),acc3.y); acc3.z=fmaf(x3,b2f(v3.z),acc3.z); acc3.w=fmaf(x3,b2f(v3.w),acc3.w);
  }
  for (; j<deg; j++){
    int sn=ssrc[beg+j];
    float e = es[(size_t)sn*4+head];
    ushort4 v = ((const ushort4*)(h1bf + (size_t)sn*F1))[lane];
    float x = __expf(leaky(e+edh));
    s0 += x;
    acc0.x=fmaf(x,b2f(v.x),acc0.x); acc0.y=fmaf(x,b2f(v.y),acc0.y);
    acc0.z=fmaf(x,b2f(v.z),acc0.z); acc0.w=fmaf(x,b2f(v.w),acc0.w);
  }
  float inv = 1.f/(s0+s1+s2+s3+1e-16f);
  float4 acc;
  acc.x = (acc0.x+acc1.x+acc2.x+acc3.x)*inv;
  acc.y = (acc0.y+acc1.y+acc2.y+acc3.y)*inv;
  acc.z = (acc0.z+acc1.z+acc2.z+acc3.z)*inv;
  acc.w = (acc0.w+acc1.w+acc2.w+acc3.w)*inv;
  float4 bb = *(const float4*)(b1 + lane*4);
  float4 o;
  o.x = elu_f(acc.x + bb.x);
  o.y = elu_f(acc.y + bb.y);
  o.z = elu_f(acc.z + bb.z);
  o.w = elu_f(acc.w + bb.w);
  ushort4 hi, lo;
  hi.x=f2b(o.x); lo.x=f2b(o.x-b2f(hi.x));
  hi.y=f2b(o.y); lo.y=f2b(o.y-b2f(hi.y));
  hi.z=f2b(o.z); lo.z=f2b(o.z-b2f(hi.z));
  hi.w=f2b(o.w); lo.w=f2b(o.w-b2f(hi.w));
  ((ushort4*)(A2hi + (size_t)d*F1))[lane] = hi;
  ((ushort4*)(A2lo + (size_t)d*F1))[lane] = lo;
}

// ---------------- layer-2 aggregation: single-pass, degree-sorted, + final mean ----------------
__global__ __launch_bounds__(256) void k_agg2(const unsigned short* __restrict__ h2bf, const float* __restrict__ es,
                       const float* __restrict__ ed, const int* __restrict__ offsets,
                       const int* __restrict__ ssrc, const int* __restrict__ perm,
                       const float* __restrict__ b2, float* __restrict__ out){
  int wave=threadIdx.x>>6, lane=threadIdx.x&63;
  int idx = blockIdx.x*4+wave; if (idx>=N_NODES) return;
  int d = perm[idx];
  int beg=offsets[d], end=offsets[d+1];
  int deg=end-beg;
  float edv = ed[d];
  float s0=0.f,s1=0.f,s2=0.f,s3=0.f;
  float2 acc0={0,0}, acc1={0,0}, acc2={0,0}, acc3={0,0};
  int j=0;
  for (; j+4<=deg; j+=4){
    int sn0=ssrc[beg+j], sn1=ssrc[beg+j+1], sn2=ssrc[beg+j+2], sn3=ssrc[beg+j+3];
    float e0=es[sn0], e1=es[sn1], e2=es[sn2], e3=es[sn3];
    ushort2 v0 = ((const ushort2*)(h2bf + (size_t)sn0*F2))[lane];
    ushort2 v1 = ((const ushort2*)(h2bf + (size_t)sn1*F2))[lane];
    ushort2 v2 = ((const ushort2*)(h2bf + (size_t)sn2*F2))[lane];
    ushort2 v3 = ((const ushort2*)(h2bf + (size_t)sn3*F2))[lane];
    float x0=__expf(leaky(e0+edv)), x1=__expf(leaky(e1+edv));
    float x2=__expf(leaky(e2+edv)), x3=__expf(leaky(e3+edv));
    s0+=x0; s1+=x1; s2+=x2; s3+=x3;
    acc0.x=fmaf(x0,b2f(v0.x),acc0.x); acc0.y=fmaf(x0,b2f(v0.y),acc0.y);
    acc1.x=fmaf(x1,b2f(v1.x),acc1.x); acc1.y=fmaf(x1,b2f(v1.y),acc1.y);
    acc2.x=fmaf(x2,b2f(v2.x),acc2.x); acc2.y=fmaf(x2,b2f(v2.y),acc2.y);
    acc3.x=fmaf(x3,b2f(v3.x),acc3.x); acc3.y=fmaf(x3,b2f(v3.y),acc3.y);
  }
  for (; j<deg; j++){
    int sn=ssrc[beg+j];
    float x = __expf(leaky(es[sn]+edv));
    ushort2 v = ((const ushort2*)(h2bf + (size_t)sn*F2))[lane];
    s0 += x;
    acc0.x=fmaf(x,b2f(v.x),acc0.x); acc0.y=fmaf(x,b2f(v.y),acc0.y);
  }
  float inv = 1.f/(s0+s1+s2+s3+1e-16f);
  float2 acc;
  acc.x = (acc0.x+acc1.x+acc2.x+acc3.x)*inv;
  acc.y = (acc0.y+acc1.y+acc2.y+acc3.y)*inv;
  float2 bb = *(const float2*)(b2 + lane*2);
  float r = elu_f(acc.x+bb.x) + elu_f(acc.y+bb.y);
  #pragma unroll
  for (int off=1;off<64;off<<=1) r += __shfl_xor(r,off);
  if (lane==0) out[d] = r * (1.f/128.f);
}

extern "C" void kernel_launch(void* const* d_in, const int* in_sizes, int n_in,
                              void* d_out, int out_size, void* d_ws, size_t ws_size,
                              hipStream_t stream) {
  const float* x   = (const float*)d_in[0];
  const int*   ei  = (const int*)d_in[1];
  const int*   esrc = ei;
  const int*   edst = ei + N_EDGES;
  const float* W1  = (const float*)d_in[2];
  const float* a1s = (const float*)d_in[3];
  const float* a1d = (const float*)d_in[4];
  const float* b1  = (const float*)d_in[5];
  const float* W2  = (const float*)d_in[6];
  const float* a2s = (const float*)d_in[7];
  const float* a2d = (const float*)d_in[8];
  const float* b2  = (const float*)d_in[9];
  float* out = (float*)d_out;

  char* ws = (char*)d_ws;
  size_t off = 0;
  auto alloc = [&](size_t bytes)->void*{ void* p = ws + off; off += (bytes + 255) & ~(size_t)255; return p; };
  unsigned short* A1hi = (unsigned short*)alloc((size_t)M_PAD*F1*2);
  unsigned short* A1lo = (unsigned short*)alloc((size_t)M_PAD*F1*2);
  unsigned short* h1bf = (unsigned short*)alloc((size_t)M_PAD*F1*2);
  unsigned short* h2bf = (unsigned short*)alloc((size_t)M_PAD*F2*2);
  unsigned short* Bt1hi= (unsigned short*)alloc((size_t)F1*DIN*2);
  unsigned short* Bt1lo= (unsigned short*)alloc((size_t)F1*DIN*2);
  unsigned short* Bt2hi= (unsigned short*)alloc((size_t)F2*F1*2);
  unsigned short* Bt2lo= (unsigned short*)alloc((size_t)F2*F1*2);
  float* e1s   = (float*)alloc((size_t)M_PAD*HEADS*4);
  float* e1d   = (float*)alloc((size_t)M_PAD*HEADS*4);
  float* e2s   = (float*)alloc((size_t)N_NODES*4);
  float* e2d   = (float*)alloc((size_t)N_NODES*4);
  int*   counts= (int*)alloc((size_t)N_NODES*4);
  int*   offs  = (int*)alloc((size_t)(N_NODES+1)*4);
  int*   cursor= (int*)alloc((size_t)N_NODES*4);
  int*   exc   = (int*)alloc((size_t)N_NODES*4);
  int*   bsum  = (int*)alloc((size_t)SCAN_NBLK*4);
  int*   bpref = (int*)alloc((size_t)SCAN_NBLK*4);
  int*   perm  = (int*)alloc((size_t)N_NODES*4);
  int*   dbin  = (int*)alloc((size_t)256*4);
  int*   dcur  = (int*)alloc((size_t)256*4);
  int*   ssrc  = (int*)alloc((size_t)EP*4);
  unsigned short* A2hi = A1hi;
  unsigned short* A2lo = A1lo;

  hipMemsetAsync(counts, 0, (size_t)N_NODES*4, stream);
  hipMemsetAsync(dbin, 0, (size_t)256*4, stream);
  k_hist<<<(EP+255)/256, 256, 0, stream>>>(edst, counts);
  k_scan1<<<SCAN_NBLK, 256, 0, stream>>>(counts, exc, bsum);
  k_scan2<<<1, 256, 0, stream>>>(bsum, bpref, offs);
  k_scan3<<<SCAN_NBLK, 256, 0, stream>>>(exc, bpref, offs, cursor);
  k_scatter<<<(EP+255)/256, 256, 0, stream>>>(esrc, edst, cursor, ssrc);
  k_dhist<<<SCAN_NBLK, 256, 0, stream>>>(counts, dbin);
  k_dscan<<<1, 256, 0, stream>>>(dbin, dcur);
  k_dscatter<<<SCAN_NBLK, 256, 0, stream>>>(counts, dcur, perm);

  k_splitA<<<(M_PAD*F1/4 + 255)/256, 256, 0, stream>>>(x, A1hi, A1lo);
  k_splitWT<<<(DIN*F1 + 255)/256, 256, 0, stream>>>(W1, Bt1hi, Bt1lo, DIN, F1);
  k_splitWT<<<(F1*F2 + 255)/256, 256, 0, stream>>>(W2, Bt2hi, Bt2lo, F1, F2);

  k_gemm1f<<<M_PAD/64, 256, 0, stream>>>(A1hi, A1lo, Bt1hi, Bt1lo, a1s, a1d, h1bf, e1s, e1d);
  k_agg1<<<(M_PAD+3)/4, 256, 0, stream>>>(h1bf, e1s, e1d, offs, ssrc, perm, b1, A2hi, A2lo);

  k_gemm_bf3<2,2><<<M_PAD/128, 256, 0, stream>>>(A2hi, A2lo, Bt2hi, Bt2lo, h2bf, F2);
  k_edot2<<<(N_NODES+3)/4, 256, 0, stream>>>(h2bf, a2s, a2d, e2s, e2d);
  k_agg2<<<(N_NODES+3)/4, 256, 0, stream>>>(h2bf, e2s, e2d, offs, ssrc, perm, b2, out);
}

// Round 7
// 365.562 us; speedup vs baseline: 1.7294x; 1.7294x over previous
//
#include <hip/hip_runtime.h>
#include <math.h>

#define N_NODES 50000
#define M_PAD   50048            /* 391*128 = 782*64 */
#define N_EDGES 800000
#define EP (N_EDGES + N_NODES)
#define DIN 256
#define HEADS 4
#define HID 64
#define F1 256
#define F2 128
#define NEG_SLOPE 0.2f
#define SCAN_NBLK ((N_NODES + 255)/256)   /* 196 */

typedef short bf16x8 __attribute__((ext_vector_type(8)));
typedef float f32x4  __attribute__((ext_vector_type(4)));

static __device__ __forceinline__ float leaky(float x){ return x > 0.f ? x : NEG_SLOPE*x; }
static __device__ __forceinline__ float elu_f(float x){ return x > 0.f ? x : (__expf(x)-1.f); }
static __device__ __forceinline__ float b2f(unsigned short u){ return __uint_as_float(((unsigned)u)<<16); }
static __device__ __forceinline__ unsigned short f2b(float f){
  unsigned u = __float_as_uint(f);
  return (unsigned short)((u + 0x7fffu + ((u>>16)&1u)) >> 16);   // RNE
}

// ---------------- CSR build ----------------
__global__ __launch_bounds__(256) void k_hist(const int* __restrict__ dst, int* __restrict__ counts){
  int e = blockIdx.x*256 + threadIdx.x;
  if (e >= EP) return;
  int d = (e < N_EDGES) ? dst[e] : (e - N_EDGES);
  atomicAdd(&counts[d], 1);
}

__global__ __launch_bounds__(256) void k_scan1(const int* __restrict__ counts,
                                               int* __restrict__ exc, int* __restrict__ bsum){
  int i = blockIdx.x*256 + threadIdx.x;
  int v = (i < N_NODES) ? counts[i] : 0;
  int lane = threadIdx.x & 63, wave = threadIdx.x >> 6;
  int inc = v;
  #pragma unroll
  for (int off=1; off<64; off<<=1){
    int n = __shfl_up(inc, off);
    if (lane >= off) inc += n;
  }
  __shared__ int wsum[4];
  if (lane == 63) wsum[wave] = inc;
  __syncthreads();
  int wpre = 0;
  #pragma unroll
  for (int w=0; w<4; w++) if (w < wave) wpre += wsum[w];
  if (i < N_NODES) exc[i] = wpre + inc - v;
  if (threadIdx.x == 255) bsum[blockIdx.x] = wpre + inc;
}

__global__ __launch_bounds__(256) void k_scan2(const int* __restrict__ bsum,
                                               int* __restrict__ bpref, int* __restrict__ offsets){
  int i = threadIdx.x;
  int v = (i < SCAN_NBLK) ? bsum[i] : 0;
  int lane = threadIdx.x & 63, wave = threadIdx.x >> 6;
  int inc = v;
  #pragma unroll
  for (int off=1; off<64; off<<=1){
    int n = __shfl_up(inc, off);
    if (lane >= off) inc += n;
  }
  __shared__ int wsum[4];
  if (lane == 63) wsum[wave] = inc;
  __syncthreads();
  int wpre = 0;
  #pragma unroll
  for (int w=0; w<4; w++) if (w < wave) wpre += wsum[w];
  if (i < SCAN_NBLK) bpref[i] = wpre + inc - v;
  if (i == 255) offsets[N_NODES] = wpre + inc;
}

__global__ __launch_bounds__(256) void k_scan3(const int* __restrict__ exc, const int* __restrict__ bpref,
                                               int* __restrict__ offsets, int* __restrict__ cursor){
  int i = blockIdx.x*256 + threadIdx.x;
  if (i >= N_NODES) return;
  int o = exc[i] + bpref[blockIdx.x];
  offsets[i] = o;
  cursor[i] = o;
}

__global__ __launch_bounds__(256) void k_scatter(const int* __restrict__ src, const int* __restrict__ dst,
                          int* __restrict__ cursor, int* __restrict__ sorted_src){
  int e = blockIdx.x*256 + threadIdx.x;
  if (e >= EP) return;
  int s, d;
  if (e < N_EDGES){ s = src[e]; d = dst[e]; } else { s = d = e - N_EDGES; }
  int pos = atomicAdd(&cursor[d], 1);
  sorted_src[pos] = s;
}

// ---------------- contention-free degree counting sort ----------------
__global__ __launch_bounds__(256) void k_dhist(const int* __restrict__ counts,
                                               int* __restrict__ dbin, int* __restrict__ bcount){
  __shared__ int h[256];
  h[threadIdx.x] = 0;
  __syncthreads();
  int i = blockIdx.x*256 + threadIdx.x;
  if (i < N_NODES){
    int b = counts[i]; if (b > 255) b = 255;
    atomicAdd(&h[b], 1);
  }
  __syncthreads();
  int c = h[threadIdx.x];
  bcount[(size_t)blockIdx.x*256 + threadIdx.x] = c;
  if (c) atomicAdd(&dbin[threadIdx.x], c);
}

__global__ __launch_bounds__(256) void k_dscan(const int* __restrict__ dbin, int* __restrict__ dbase){
  int i = threadIdx.x;
  int v = dbin[i];
  int lane = threadIdx.x & 63, wave = threadIdx.x >> 6;
  int inc = v;
  #pragma unroll
  for (int off=1; off<64; off<<=1){
    int n = __shfl_up(inc, off);
    if (lane >= off) inc += n;
  }
  __shared__ int wsum[4];
  if (lane == 63) wsum[wave] = inc;
  __syncthreads();
  int wpre = 0;
  #pragma unroll
  for (int w=0; w<4; w++) if (w < wave) wpre += wsum[w];
  dbase[i] = wpre + inc - v;
}

__global__ __launch_bounds__(256) void k_dcol(const int* __restrict__ bcount, const int* __restrict__ dbase,
                                              int* __restrict__ colbase){
  int bin = threadIdx.x;           // one thread per bin; reads coalesced across bins
  int run = dbase[bin];
  for (int blk=0; blk<SCAN_NBLK; blk++){
    colbase[(size_t)blk*256 + bin] = run;
    run += bcount[(size_t)blk*256 + bin];
  }
}

__global__ __launch_bounds__(256) void k_dscatter(const int* __restrict__ counts, const int* __restrict__ colbase,
                                                  int* __restrict__ perm){
  __shared__ int h[256];
  h[threadIdx.x] = 0;
  __syncthreads();
  int i = blockIdx.x*256 + threadIdx.x;
  if (i < N_NODES){
    int b = counts[i]; if (b > 255) b = 255;
    int r = atomicAdd(&h[b], 1);                  // LDS rank — fast
    perm[colbase[(size_t)blockIdx.x*256 + b] + r] = i;
  }
}

// ---------------- split f32 -> bf16 hi/lo ----------------
__global__ __launch_bounds__(256) void k_splitA(const float* __restrict__ X,
                         unsigned short* __restrict__ Ahi, unsigned short* __restrict__ Alo){
  int gid = blockIdx.x*256 + threadIdx.x;
  size_t base = (size_t)gid*4;
  int row = (int)(base >> 8);
  ushort4 hi, lo;
  if (row < N_NODES){
    float4 v = *(const float4*)(X + base);
    hi.x=f2b(v.x); hi.y=f2b(v.y); hi.z=f2b(v.z); hi.w=f2b(v.w);
    lo.x=f2b(v.x-b2f(hi.x)); lo.y=f2b(v.y-b2f(hi.y));
    lo.z=f2b(v.z-b2f(hi.z)); lo.w=f2b(v.w-b2f(hi.w));
  } else {
    hi = {0,0,0,0}; lo = {0,0,0,0};
  }
  *(ushort4*)(Ahi + base) = hi;
  *(ushort4*)(Alo + base) = lo;
}

__global__ __launch_bounds__(256) void k_splitWT(const float* __restrict__ W,
                          unsigned short* __restrict__ Bhi, unsigned short* __restrict__ Blo,
                          int Kd, int Nd){
  int t = blockIdx.x*256 + threadIdx.x;
  if (t >= Kd*Nd) return;
  int n = t / Kd, k = t % Kd;
  float v = W[(size_t)k*Nd + n];
  unsigned short hi = f2b(v);
  unsigned short lo = f2b(v - b2f(hi));
  Bhi[(size_t)n*Kd + k] = hi;
  Blo[(size_t)n*Kd + k] = lo;
}

// ---------------- GEMM1 (WR=1, WC=4) with fused edot1 epilogue ----------------
__global__ __launch_bounds__(256) void k_gemm1f(
    const unsigned short* __restrict__ Ahi, const unsigned short* __restrict__ Alo,
    const unsigned short* __restrict__ Bthi, const unsigned short* __restrict__ Btlo,
    const float* __restrict__ a1s, const float* __restrict__ a1d,
    unsigned short* __restrict__ Cbf, float* __restrict__ es, float* __restrict__ ed){
  const int K = 256, Nc = F1;
  int tid = threadIdx.x;
  int wave = tid>>6, lane = tid&63;
  int wc = wave;                 // head index
  int row0 = blockIdx.x*64;
  int col0 = wc*64;
  int lrow = lane&15, lk = (lane>>4)*8;
  f32x4 acc[4][4] = {};
  for (int ks=0; ks<K; ks+=32){
    bf16x8 ah[4], al[4], bh[4], bl[4];
    #pragma unroll
    for (int i=0;i<4;i++){
      size_t aoff = (size_t)(row0 + i*16 + lrow)*K + ks + lk;
      ah[i] = *(const bf16x8*)(Ahi + aoff);
      al[i] = *(const bf16x8*)(Alo + aoff);
      size_t boff = (size_t)(col0 + i*16 + lrow)*K + ks + lk;
      bh[i] = *(const bf16x8*)(Bthi + boff);
      bl[i] = *(const bf16x8*)(Btlo + boff);
    }
    #pragma unroll
    for (int i=0;i<4;i++)
      #pragma unroll
      for (int j=0;j<4;j++)
        acc[i][j] = __builtin_amdgcn_mfma_f32_16x16x32_bf16(ah[i], bh[j], acc[i][j], 0,0,0);
    #pragma unroll
    for (int i=0;i<4;i++)
      #pragma unroll
      for (int j=0;j<4;j++)
        acc[i][j] = __builtin_amdgcn_mfma_f32_16x16x32_bf16(ah[i], bl[j], acc[i][j], 0,0,0);
    #pragma unroll
    for (int i=0;i<4;i++)
      #pragma unroll
      for (int j=0;j<4;j++)
        acc[i][j] = __builtin_amdgcn_mfma_f32_16x16x32_bf16(al[i], bh[j], acc[i][j], 0,0,0);
  }
  int crow = (lane>>4)*4, ccol = lane&15;
  #pragma unroll
  for (int i=0;i<4;i++)
    #pragma unroll
    for (int j=0;j<4;j++)
      #pragma unroll
      for (int q=0;q<4;q++){
        int r = row0 + i*16 + crow + q;
        int c = col0 + j*16 + ccol;
        Cbf[(size_t)r*Nc + c] = f2b(acc[i][j][q]);
      }
  // fused edot: wave wc owns head wc's 64 cols entirely
  float avs[4], avd[4];
  #pragma unroll
  for (int j=0;j<4;j++){
    avs[j] = a1s[wc*64 + j*16 + ccol];
    avd[j] = a1d[wc*64 + j*16 + ccol];
  }
  #pragma unroll
  for (int i=0;i<4;i++){
    #pragma unroll
    for (int q=0;q<4;q++){
      float ps = acc[i][0][q]*avs[0] + acc[i][1][q]*avs[1] + acc[i][2][q]*avs[2] + acc[i][3][q]*avs[3];
      float pd = acc[i][0][q]*avd[0] + acc[i][1][q]*avd[1] + acc[i][2][q]*avd[2] + acc[i][3][q]*avd[3];
      #pragma unroll
      for (int off=1; off<16; off<<=1){ ps += __shfl_xor(ps,off); pd += __shfl_xor(pd,off); }
      if ((lane&15)==0){
        int r = row0 + i*16 + crow + q;
        es[(size_t)r*4 + wc] = ps;
        ed[(size_t)r*4 + wc] = pd;
      }
    }
  }
}

// ---------------- plain GEMM (for layer 2) ----------------
template<int WR, int WC>
__global__ __launch_bounds__(256) void k_gemm_bf3(
    const unsigned short* __restrict__ Ahi, const unsigned short* __restrict__ Alo,
    const unsigned short* __restrict__ Bthi, const unsigned short* __restrict__ Btlo,
    unsigned short* __restrict__ Cbf, int Nc){
  const int K = 256;
  int tid = threadIdx.x;
  int wave = tid>>6, lane = tid&63;
  int wr = wave / WC, wc = wave % WC;
  int row0 = blockIdx.x*(WR*64) + wr*64;
  int col0 = blockIdx.y*(WC*64) + wc*64;
  int lrow = lane&15, lk = (lane>>4)*8;
  f32x4 acc[4][4] = {};
  for (int ks=0; ks<K; ks+=32){
    bf16x8 ah[4], al[4], bh[4], bl[4];
    #pragma unroll
    for (int i=0;i<4;i++){
      size_t aoff = (size_t)(row0 + i*16 + lrow)*K + ks + lk;
      ah[i] = *(const bf16x8*)(Ahi + aoff);
      al[i] = *(const bf16x8*)(Alo + aoff);
      size_t boff = (size_t)(col0 + i*16 + lrow)*K + ks + lk;
      bh[i] = *(const bf16x8*)(Bthi + boff);
      bl[i] = *(const bf16x8*)(Btlo + boff);
    }
    #pragma unroll
    for (int i=0;i<4;i++)
      #pragma unroll
      for (int j=0;j<4;j++)
        acc[i][j] = __builtin_amdgcn_mfma_f32_16x16x32_bf16(ah[i], bh[j], acc[i][j], 0,0,0);
    #pragma unroll
    for (int i=0;i<4;i++)
      #pragma unroll
      for (int j=0;j<4;j++)
        acc[i][j] = __builtin_amdgcn_mfma_f32_16x16x32_bf16(ah[i], bl[j], acc[i][j], 0,0,0);
    #pragma unroll
    for (int i=0;i<4;i++)
      #pragma unroll
      for (int j=0;j<4;j++)
        acc[i][j] = __builtin_amdgcn_mfma_f32_16x16x32_bf16(al[i], bh[j], acc[i][j], 0,0,0);
  }
  int crow = (lane>>4)*4, ccol = lane&15;
  #pragma unroll
  for (int i=0;i<4;i++)
    #pragma unroll
    for (int j=0;j<4;j++)
      #pragma unroll
      for (int q=0;q<4;q++){
        int r = row0 + i*16 + crow + q;
        int c = col0 + j*16 + ccol;
        Cbf[(size_t)r*Nc + c] = f2b(acc[i][j][q]);
      }
}

// ---------------- edot2 ----------------
__global__ __launch_bounds__(256) void k_edot2(const unsigned short* __restrict__ h2bf, const float* __restrict__ a_src,
                        const float* __restrict__ a_dst, float* __restrict__ es, float* __restrict__ ed){
  int wave=threadIdx.x>>6, lane=threadIdx.x&63;
  int n = blockIdx.x*4+wave; if (n>=N_NODES) return;
  ushort2 hv = ((const ushort2*)(h2bf + (size_t)n*F2))[lane];
  float2 s2 = ((const float2*)a_src)[lane];
  float2 d2 = ((const float2*)a_dst)[lane];
  float h0=b2f(hv.x), h1=b2f(hv.y);
  float ps = h0*s2.x + h1*s2.y;
  float pd = h0*d2.x + h1*d2.y;
  #pragma unroll
  for (int m=1;m<64;m<<=1){ ps += __shfl_xor(ps,m); pd += __shfl_xor(pd,m); }
  if (lane==0){ es[n]=ps; ed[n]=pd; }
}

// ---------------- layer-1 aggregation: single-pass, degree-sorted ----------------
__global__ __launch_bounds__(256) void k_agg1(const unsigned short* __restrict__ h1bf, const float* __restrict__ es,
                       const float* __restrict__ ed, const int* __restrict__ offsets,
                       const int* __restrict__ ssrc, const int* __restrict__ perm,
                       const float* __restrict__ b1,
                       unsigned short* __restrict__ A2hi, unsigned short* __restrict__ A2lo){
  int wave = threadIdx.x>>6, lane = threadIdx.x&63;
  int idx = blockIdx.x*4 + wave;
  if (idx >= M_PAD) return;
  if (idx >= N_NODES){                       // pad rows: zero for GEMM2
    ushort4 z = {0,0,0,0};
    ((ushort4*)(A2hi + (size_t)idx*F1))[lane] = z;
    ((ushort4*)(A2lo + (size_t)idx*F1))[lane] = z;
    return;
  }
  int d = perm[idx];
  int beg = offsets[d], end = offsets[d+1];
  int deg = end - beg;
  float4 edv = *(const float4*)(ed + (size_t)d*4);
  int head = lane>>4;
  float edh = head==0?edv.x:(head==1?edv.y:(head==2?edv.z:edv.w));
  float s0=0.f,s1=0.f,s2=0.f,s3=0.f;
  float4 acc0={0,0,0,0}, acc1={0,0,0,0}, acc2={0,0,0,0}, acc3={0,0,0,0};
  int j=0;
  for (; j+4<=deg; j+=4){
    int sn0=ssrc[beg+j], sn1=ssrc[beg+j+1], sn2=ssrc[beg+j+2], sn3=ssrc[beg+j+3];
    float e0 = es[(size_t)sn0*4+head], e1 = es[(size_t)sn1*4+head];
    float e2 = es[(size_t)sn2*4+head], e3 = es[(size_t)sn3*4+head];
    ushort4 v0 = ((const ushort4*)(h1bf + (size_t)sn0*F1))[lane];
    ushort4 v1 = ((const ushort4*)(h1bf + (size_t)sn1*F1))[lane];
    ushort4 v2 = ((const ushort4*)(h1bf + (size_t)sn2*F1))[lane];
    ushort4 v3 = ((const ushort4*)(h1bf + (size_t)sn3*F1))[lane];
    float x0 = __expf(leaky(e0+edh)), x1 = __expf(leaky(e1+edh));
    float x2 = __expf(leaky(e2+edh)), x3 = __expf(leaky(e3+edh));
    s0+=x0; s1+=x1; s2+=x2; s3+=x3;
    acc0.x=fmaf(x0,b2f(v0.x),acc0.x); acc0.y=fmaf(x0,b2f(v0.y),acc0.y); acc0.z=fmaf(x0,b2f(v0.z),acc0.z); acc0.w=fmaf(x0,b2f(v0.w),acc0.w);
    acc1.x=fmaf(x1,b2f(v1.x),acc1.x); acc1.y=fmaf(x1,b2f(v1.y),acc1.y); acc1.z=fmaf(x1,b2f(v1.z),acc1.z); acc1.w=fmaf(x1,b2f(v1.w),acc1.w);
    acc2.x=fmaf(x2,b2f(v2.x),acc2.x); acc2.y=fmaf(x2,b2f(v2.y),acc2.y); acc2.z=fmaf(x2,b2f(v2.z),acc2.z); acc2.w=fmaf(x2,b2f(v2.w),acc2.w);
    acc3.x=fmaf(x3,b2f(v3.x),acc3.x); acc3.y=fmaf(x3,b2f(v3.y),acc3.y); acc3.z=fmaf(x3,b2f(v3.z),acc3.z); acc3.w=fmaf(x3,b2f(v3.w),acc3.w);
  }
  for (; j<deg; j++){
    int sn=ssrc[beg+j];
    float e = es[(size_t)sn*4+head];
    ushort4 v = ((const ushort4*)(h1bf + (size_t)sn*F1))[lane];
    float x = __expf(leaky(e+edh));
    s0 += x;
    acc0.x=fmaf(x,b2f(v.x),acc0.x); acc0.y=fmaf(x,b2f(v.y),acc0.y);
    acc0.z=fmaf(x,b2f(v.z),acc0.z); acc0.w=fmaf(x,b2f(v.w),acc0.w);
  }
  float inv = 1.f/(s0+s1+s2+s3+1e-16f);
  float4 acc;
  acc.x = (acc0.x+acc1.x+acc2.x+acc3.x)*inv;
  acc.y = (acc0.y+acc1.y+acc2.y+acc3.y)*inv;
  acc.z = (acc0.z+acc1.z+acc2.z+acc3.z)*inv;
  acc.w = (acc0.w+acc1.w+acc2.w+acc3.w)*inv;
  float4 bb = *(const float4*)(b1 + lane*4);
  float4 o;
  o.x = elu_f(acc.x + bb.x);
  o.y = elu_f(acc.y + bb.y);
  o.z = elu_f(acc.z + bb.z);
  o.w = elu_f(acc.w + bb.w);
  ushort4 hi, lo;
  hi.x=f2b(o.x); lo.x=f2b(o.x-b2f(hi.x));
  hi.y=f2b(o.y); lo.y=f2b(o.y-b2f(hi.y));
  hi.z=f2b(o.z); lo.z=f2b(o.z-b2f(hi.z));
  hi.w=f2b(o.w); lo.w=f2b(o.w-b2f(hi.w));
  ((ushort4*)(A2hi + (size_t)d*F1))[lane] = hi;
  ((ushort4*)(A2lo + (size_t)d*F1))[lane] = lo;
}

// ---------------- layer-2 aggregation: single-pass, degree-sorted, + final mean ----------------
__global__ __launch_bounds__(256) void k_agg2(const unsigned short* __restrict__ h2bf, const float* __restrict__ es,
                       const float* __restrict__ ed, const int* __restrict__ offsets,
                       const int* __restrict__ ssrc, const int* __restrict__ perm,
                       const float* __restrict__ b2, float* __restrict__ out){
  int wave=threadIdx.x>>6, lane=threadIdx.x&63;
  int idx = blockIdx.x*4+wave; if (idx>=N_NODES) return;
  int d = perm[idx];
  int beg=offsets[d], end=offsets[d+1];
  int deg=end-beg;
  float edv = ed[d];
  float s0=0.f,s1=0.f,s2=0.f,s3=0.f;
  float2 acc0={0,0}, acc1={0,0}, acc2={0,0}, acc3={0,0};
  int j=0;
  for (; j+4<=deg; j+=4){
    int sn0=ssrc[beg+j], sn1=ssrc[beg+j+1], sn2=ssrc[beg+j+2], sn3=ssrc[beg+j+3];
    float e0=es[sn0], e1=es[sn1], e2=es[sn2], e3=es[sn3];
    ushort2 v0 = ((const ushort2*)(h2bf + (size_t)sn0*F2))[lane];
    ushort2 v1 = ((const ushort2*)(h2bf + (size_t)sn1*F2))[lane];
    ushort2 v2 = ((const ushort2*)(h2bf + (size_t)sn2*F2))[lane];
    ushort2 v3 = ((const ushort2*)(h2bf + (size_t)sn3*F2))[lane];
    float x0=__expf(leaky(e0+edv)), x1=__expf(leaky(e1+edv));
    float x2=__expf(leaky(e2+edv)), x3=__expf(leaky(e3+edv));
    s0+=x0; s1+=x1; s2+=x2; s3+=x3;
    acc0.x=fmaf(x0,b2f(v0.x),acc0.x); acc0.y=fmaf(x0,b2f(v0.y),acc0.y);
    acc1.x=fmaf(x1,b2f(v1.x),acc1.x); acc1.y=fmaf(x1,b2f(v1.y),acc1.y);
    acc2.x=fmaf(x2,b2f(v2.x),acc2.x); acc2.y=fmaf(x2,b2f(v2.y),acc2.y);
    acc3.x=fmaf(x3,b2f(v3.x),acc3.x); acc3.y=fmaf(x3,b2f(v3.y),acc3.y);
  }
  for (; j<deg; j++){
    int sn=ssrc[beg+j];
    float x = __expf(leaky(es[sn]+edv));
    ushort2 v = ((const ushort2*)(h2bf + (size_t)sn*F2))[lane];
    s0 += x;
    acc0.x=fmaf(x,b2f(v.x),acc0.x); acc0.y=fmaf(x,b2f(v.y),acc0.y);
  }
  float inv = 1.f/(s0+s1+s2+s3+1e-16f);
  float2 acc;
  acc.x = (acc0.x+acc1.x+acc2.x+acc3.x)*inv;
  acc.y = (acc0.y+acc1.y+acc2.y+acc3.y)*inv;
  float2 bb = *(const float2*)(b2 + lane*2);
  float r = elu_f(acc.x+bb.x) + elu_f(acc.y+bb.y);
  #pragma unroll
  for (int off=1;off<64;off<<=1) r += __shfl_xor(r,off);
  if (lane==0) out[d] = r * (1.f/128.f);
}

extern "C" void kernel_launch(void* const* d_in, const int* in_sizes, int n_in,
                              void* d_out, int out_size, void* d_ws, size_t ws_size,
                              hipStream_t stream) {
  const float* x   = (const float*)d_in[0];
  const int*   ei  = (const int*)d_in[1];
  const int*   esrc = ei;
  const int*   edst = ei + N_EDGES;
  const float* W1  = (const float*)d_in[2];
  const float* a1s = (const float*)d_in[3];
  const float* a1d = (const float*)d_in[4];
  const float* b1  = (const float*)d_in[5];
  const float* W2  = (const float*)d_in[6];
  const float* a2s = (const float*)d_in[7];
  const float* a2d = (const float*)d_in[8];
  const float* b2  = (const float*)d_in[9];
  float* out = (float*)d_out;

  char* ws = (char*)d_ws;
  size_t off = 0;
  auto alloc = [&](size_t bytes)->void*{ void* p = ws + off; off += (bytes + 255) & ~(size_t)255; return p; };
  unsigned short* A1hi = (unsigned short*)alloc((size_t)M_PAD*F1*2);
  unsigned short* A1lo = (unsigned short*)alloc((size_t)M_PAD*F1*2);
  unsigned short* h1bf = (unsigned short*)alloc((size_t)M_PAD*F1*2);
  unsigned short* h2bf = (unsigned short*)alloc((size_t)M_PAD*F2*2);
  unsigned short* Bt1hi= (unsigned short*)alloc((size_t)F1*DIN*2);
  unsigned short* Bt1lo= (unsigned short*)alloc((size_t)F1*DIN*2);
  unsigned short* Bt2hi= (unsigned short*)alloc((size_t)F2*F1*2);
  unsigned short* Bt2lo= (unsigned short*)alloc((size_t)F2*F1*2);
  float* e1s   = (float*)alloc((size_t)M_PAD*HEADS*4);
  float* e1d   = (float*)alloc((size_t)M_PAD*HEADS*4);
  float* e2s   = (float*)alloc((size_t)N_NODES*4);
  float* e2d   = (float*)alloc((size_t)N_NODES*4);
  int*   counts= (int*)alloc((size_t)N_NODES*4);
  int*   offs  = (int*)alloc((size_t)(N_NODES+1)*4);
  int*   cursor= (int*)alloc((size_t)N_NODES*4);
  int*   exc   = (int*)alloc((size_t)N_NODES*4);
  int*   bsum  = (int*)alloc((size_t)SCAN_NBLK*4);
  int*   bpref = (int*)alloc((size_t)SCAN_NBLK*4);
  int*   perm  = (int*)alloc((size_t)N_NODES*4);
  int*   dbin  = (int*)alloc((size_t)256*4);
  int*   dbase = (int*)alloc((size_t)256*4);
  int*   bcount= (int*)alloc((size_t)SCAN_NBLK*256*4);
  int*   colbase=(int*)alloc((size_t)SCAN_NBLK*256*4);
  int*   ssrc  = (int*)alloc((size_t)EP*4);
  unsigned short* A2hi = A1hi;
  unsigned short* A2lo = A1lo;

  hipMemsetAsync(counts, 0, (size_t)N_NODES*4, stream);
  hipMemsetAsync(dbin, 0, (size_t)256*4, stream);
  k_hist<<<(EP+255)/256, 256, 0, stream>>>(edst, counts);
  k_scan1<<<SCAN_NBLK, 256, 0, stream>>>(counts, exc, bsum);
  k_scan2<<<1, 256, 0, stream>>>(bsum, bpref, offs);
  k_scan3<<<SCAN_NBLK, 256, 0, stream>>>(exc, bpref, offs, cursor);
  k_scatter<<<(EP+255)/256, 256, 0, stream>>>(esrc, edst, cursor, ssrc);
  k_dhist<<<SCAN_NBLK, 256, 0, stream>>>(counts, dbin, bcount);
  k_dscan<<<1, 256, 0, stream>>>(dbin, dbase);
  k_dcol<<<1, 256, 0, stream>>>(bcount, dbase, colbase);
  k_dscatter<<<SCAN_NBLK, 256, 0, stream>>>(counts, colbase, perm);

  k_splitA<<<(M_PAD*F1/4 + 255)/256, 256, 0, stream>>>(x, A1hi, A1lo);
  k_splitWT<<<(DIN*F1 + 255)/256, 256, 0, stream>>>(W1, Bt1hi, Bt1lo, DIN, F1);
  k_splitWT<<<(F1*F2 + 255)/256, 256, 0, stream>>>(W2, Bt2hi, Bt2lo, F1, F2);

  k_gemm1f<<<M_PAD/64, 256, 0, stream>>>(A1hi, A1lo, Bt1hi, Bt1lo, a1s, a1d, h1bf, e1s, e1d);
  k_agg1<<<(M_PAD+3)/4, 256, 0, stream>>>(h1bf, e1s, e1d, offs, ssrc, perm, b1, A2hi, A2lo);

  k_gemm_bf3<2,2><<<M_PAD/128, 256, 0, stream>>>(A2hi, A2lo, Bt2hi, Bt2lo, h2bf, F2);
  k_edot2<<<(N_NODES+3)/4, 256, 0, stream>>>(h2bf, a2s, a2d, e2s, e2d);
  k_agg2<<<(N_NODES+3)/4, 256, 0, stream>>>(h2bf, e2s, e2d, offs, ssrc, perm, b2, out);
}

// Round 8
// 329.205 us; speedup vs baseline: 1.9204x; 1.1104x over previous
//
#include <hip/hip_runtime.h>
#include <math.h>

#define N_NODES 50000
#define M_PAD   50048            /* 391*128 = 782*64 */
#define N_EDGES 800000
#define EP (N_EDGES + N_NODES)
#define DIN 256
#define HEADS 4
#define HID 64
#define F1 256
#define F2 128
#define NEG_SLOPE 0.2f
#define SCAN_NBLK ((N_NODES + 255)/256)   /* 196 */

typedef short bf16x8 __attribute__((ext_vector_type(8)));
typedef float f32x4  __attribute__((ext_vector_type(4)));

static __device__ __forceinline__ float leaky(float x){ return x > 0.f ? x : NEG_SLOPE*x; }
static __device__ __forceinline__ float elu_f(float x){ return x > 0.f ? x : (__expf(x)-1.f); }
static __device__ __forceinline__ float b2f(unsigned short u){ return __uint_as_float(((unsigned)u)<<16); }
static __device__ __forceinline__ unsigned short f2b(float f){
  unsigned u = __float_as_uint(f);
  return (unsigned short)((u + 0x7fffu + ((u>>16)&1u)) >> 16);   // RNE
}

// ---------------- CSR build ----------------
__global__ __launch_bounds__(256) void k_hist(const int* __restrict__ dst, int* __restrict__ counts){
  int e = blockIdx.x*256 + threadIdx.x;
  if (e >= EP) return;
  int d = (e < N_EDGES) ? dst[e] : (e - N_EDGES);
  atomicAdd(&counts[d], 1);
}

__global__ __launch_bounds__(256) void k_scan1(const int* __restrict__ counts,
                                               int* __restrict__ exc, int* __restrict__ bsum){
  int i = blockIdx.x*256 + threadIdx.x;
  int v = (i < N_NODES) ? counts[i] : 0;
  int lane = threadIdx.x & 63, wave = threadIdx.x >> 6;
  int inc = v;
  #pragma unroll
  for (int off=1; off<64; off<<=1){
    int n = __shfl_up(inc, off);
    if (lane >= off) inc += n;
  }
  __shared__ int wsum[4];
  if (lane == 63) wsum[wave] = inc;
  __syncthreads();
  int wpre = 0;
  #pragma unroll
  for (int w=0; w<4; w++) if (w < wave) wpre += wsum[w];
  if (i < N_NODES) exc[i] = wpre + inc - v;
  if (threadIdx.x == 255) bsum[blockIdx.x] = wpre + inc;
}

__global__ __launch_bounds__(256) void k_scan2(const int* __restrict__ bsum,
                                               int* __restrict__ bpref, int* __restrict__ offsets){
  int i = threadIdx.x;
  int v = (i < SCAN_NBLK) ? bsum[i] : 0;
  int lane = threadIdx.x & 63, wave = threadIdx.x >> 6;
  int inc = v;
  #pragma unroll
  for (int off=1; off<64; off<<=1){
    int n = __shfl_up(inc, off);
    if (lane >= off) inc += n;
  }
  __shared__ int wsum[4];
  if (lane == 63) wsum[wave] = inc;
  __syncthreads();
  int wpre = 0;
  #pragma unroll
  for (int w=0; w<4; w++) if (w < wave) wpre += wsum[w];
  if (i < SCAN_NBLK) bpref[i] = wpre + inc - v;
  if (i == 255) offsets[N_NODES] = wpre + inc;
}

__global__ __launch_bounds__(256) void k_scan3(const int* __restrict__ exc, const int* __restrict__ bpref,
                                               int* __restrict__ offsets, int* __restrict__ cursor){
  int i = blockIdx.x*256 + threadIdx.x;
  if (i >= N_NODES) return;
  int o = exc[i] + bpref[blockIdx.x];
  offsets[i] = o;
  cursor[i] = o;
}

__global__ __launch_bounds__(256) void k_scatter(const int* __restrict__ src, const int* __restrict__ dst,
                          int* __restrict__ cursor, int* __restrict__ sorted_src){
  int e = blockIdx.x*256 + threadIdx.x;
  if (e >= EP) return;
  int s, d;
  if (e < N_EDGES){ s = src[e]; d = dst[e]; } else { s = d = e - N_EDGES; }
  int pos = atomicAdd(&cursor[d], 1);
  sorted_src[pos] = s;
}

// ---------------- contention-free degree counting sort ----------------
__global__ __launch_bounds__(256) void k_dhist(const int* __restrict__ counts,
                                               int* __restrict__ dbin, int* __restrict__ bcount){
  __shared__ int h[256];
  h[threadIdx.x] = 0;
  __syncthreads();
  int i = blockIdx.x*256 + threadIdx.x;
  if (i < N_NODES){
    int b = counts[i]; if (b > 255) b = 255;
    atomicAdd(&h[b], 1);
  }
  __syncthreads();
  int c = h[threadIdx.x];
  bcount[(size_t)blockIdx.x*256 + threadIdx.x] = c;
  if (c) atomicAdd(&dbin[threadIdx.x], c);
}

__global__ __launch_bounds__(256) void k_dscan(const int* __restrict__ dbin, int* __restrict__ dbase){
  int i = threadIdx.x;
  int v = dbin[i];
  int lane = threadIdx.x & 63, wave = threadIdx.x >> 6;
  int inc = v;
  #pragma unroll
  for (int off=1; off<64; off<<=1){
    int n = __shfl_up(inc, off);
    if (lane >= off) inc += n;
  }
  __shared__ int wsum[4];
  if (lane == 63) wsum[wave] = inc;
  __syncthreads();
  int wpre = 0;
  #pragma unroll
  for (int w=0; w<4; w++) if (w < wave) wpre += wsum[w];
  dbase[i] = wpre + inc - v;
}

__global__ __launch_bounds__(256) void k_dcol(const int* __restrict__ bcount, const int* __restrict__ dbase,
                                              int* __restrict__ colbase){
  int bin = threadIdx.x;
  int run = dbase[bin];
  for (int blk=0; blk<SCAN_NBLK; blk++){
    colbase[(size_t)blk*256 + bin] = run;
    run += bcount[(size_t)blk*256 + bin];
  }
}

__global__ __launch_bounds__(256) void k_dscatter(const int* __restrict__ counts, const int* __restrict__ colbase,
                                                  int* __restrict__ perm){
  __shared__ int h[256];
  h[threadIdx.x] = 0;
  __syncthreads();
  int i = blockIdx.x*256 + threadIdx.x;
  if (i < N_NODES){
    int b = counts[i]; if (b > 255) b = 255;
    int r = atomicAdd(&h[b], 1);
    perm[colbase[(size_t)blockIdx.x*256 + b] + r] = i;
  }
}

// ---------------- f32 -> bf16 (padded rows zeroed) ----------------
__global__ __launch_bounds__(256) void k_splitA(const float* __restrict__ X,
                         unsigned short* __restrict__ Ahi){
  int gid = blockIdx.x*256 + threadIdx.x;
  size_t base = (size_t)gid*4;
  int row = (int)(base >> 8);
  ushort4 hi;
  if (row < N_NODES){
    float4 v = *(const float4*)(X + base);
    hi.x=f2b(v.x); hi.y=f2b(v.y); hi.z=f2b(v.z); hi.w=f2b(v.w);
  } else {
    hi = {0,0,0,0};
  }
  *(ushort4*)(Ahi + base) = hi;
}

// W [Kd][Nd] f32 -> Bt [Nd][Kd] bf16 (transpose)
__global__ __launch_bounds__(256) void k_splitWT(const float* __restrict__ W,
                          unsigned short* __restrict__ Bhi, int Kd, int Nd){
  int t = blockIdx.x*256 + threadIdx.x;
  if (t >= Kd*Nd) return;
  int n = t / Kd, k = t % Kd;
  Bhi[(size_t)n*Kd + k] = f2b(W[(size_t)k*Nd + n]);
}

// ---------------- GEMM1 bf16 (WR=1, WC=4) + fused edot1, 2-stage prefetch ----------------
__global__ __launch_bounds__(256) void k_gemm1f(
    const unsigned short* __restrict__ A, const unsigned short* __restrict__ Bt,
    const float* __restrict__ a1s, const float* __restrict__ a1d,
    unsigned short* __restrict__ Cbf, float* __restrict__ es, float* __restrict__ ed){
  const int K = 256, Nc = F1;
  int tid = threadIdx.x;
  int wave = tid>>6, lane = tid&63;
  int wc = wave;                 // head
  int row0 = blockIdx.x*64;
  int col0 = wc*64;
  int lrow = lane&15, lk = (lane>>4)*8;
  f32x4 acc[4][4] = {};
  bf16x8 aA[4], bA[4], aB[4], bB[4];
  auto LOADF = [&](bf16x8* av, bf16x8* bv, int KS){
    #pragma unroll
    for (int i=0;i<4;i++){
      av[i] = *(const bf16x8*)(A  + (size_t)(row0 + i*16 + lrow)*K + KS + lk);
      bv[i] = *(const bf16x8*)(Bt + (size_t)(col0 + i*16 + lrow)*K + KS + lk);
    }
  };
  auto MFMAS = [&](bf16x8* av, bf16x8* bv){
    #pragma unroll
    for (int i=0;i<4;i++)
      #pragma unroll
      for (int j=0;j<4;j++)
        acc[i][j] = __builtin_amdgcn_mfma_f32_16x16x32_bf16(av[i], bv[j], acc[i][j], 0,0,0);
  };
  LOADF(aA,bA,0);
  #pragma unroll
  for (int ks=0; ks<K; ks+=64){
    LOADF(aB,bB,ks+32);
    MFMAS(aA,bA);
    if (ks+64 < K) LOADF(aA,bA,ks+64);
    MFMAS(aB,bB);
  }
  int crow = (lane>>4)*4, ccol = lane&15;
  #pragma unroll
  for (int i=0;i<4;i++)
    #pragma unroll
    for (int j=0;j<4;j++)
      #pragma unroll
      for (int q=0;q<4;q++){
        int r = row0 + i*16 + crow + q;
        int c = col0 + j*16 + ccol;
        Cbf[(size_t)r*Nc + c] = f2b(acc[i][j][q]);
      }
  float avs[4], avd[4];
  #pragma unroll
  for (int j=0;j<4;j++){
    avs[j] = a1s[wc*64 + j*16 + ccol];
    avd[j] = a1d[wc*64 + j*16 + ccol];
  }
  #pragma unroll
  for (int i=0;i<4;i++){
    #pragma unroll
    for (int q=0;q<4;q++){
      float ps = acc[i][0][q]*avs[0] + acc[i][1][q]*avs[1] + acc[i][2][q]*avs[2] + acc[i][3][q]*avs[3];
      float pd = acc[i][0][q]*avd[0] + acc[i][1][q]*avd[1] + acc[i][2][q]*avd[2] + acc[i][3][q]*avd[3];
      #pragma unroll
      for (int off=1; off<16; off<<=1){ ps += __shfl_xor(ps,off); pd += __shfl_xor(pd,off); }
      if ((lane&15)==0){
        int r = row0 + i*16 + crow + q;
        es[(size_t)r*4 + wc] = ps;
        ed[(size_t)r*4 + wc] = pd;
      }
    }
  }
}

// ---------------- plain bf16 GEMM (layer 2), 2-stage prefetch ----------------
template<int WR, int WC>
__global__ __launch_bounds__(256) void k_gemm_bf(
    const unsigned short* __restrict__ A, const unsigned short* __restrict__ Bt,
    unsigned short* __restrict__ Cbf, int Nc){
  const int K = 256;
  int tid = threadIdx.x;
  int wave = tid>>6, lane = tid&63;
  int wr = wave / WC, wc = wave % WC;
  int row0 = blockIdx.x*(WR*64) + wr*64;
  int col0 = blockIdx.y*(WC*64) + wc*64;
  int lrow = lane&15, lk = (lane>>4)*8;
  f32x4 acc[4][4] = {};
  bf16x8 aA[4], bA[4], aB[4], bB[4];
  auto LOADF = [&](bf16x8* av, bf16x8* bv, int KS){
    #pragma unroll
    for (int i=0;i<4;i++){
      av[i] = *(const bf16x8*)(A  + (size_t)(row0 + i*16 + lrow)*K + KS + lk);
      bv[i] = *(const bf16x8*)(Bt + (size_t)(col0 + i*16 + lrow)*K + KS + lk);
    }
  };
  auto MFMAS = [&](bf16x8* av, bf16x8* bv){
    #pragma unroll
    for (int i=0;i<4;i++)
      #pragma unroll
      for (int j=0;j<4;j++)
        acc[i][j] = __builtin_amdgcn_mfma_f32_16x16x32_bf16(av[i], bv[j], acc[i][j], 0,0,0);
  };
  LOADF(aA,bA,0);
  #pragma unroll
  for (int ks=0; ks<K; ks+=64){
    LOADF(aB,bB,ks+32);
    MFMAS(aA,bA);
    if (ks+64 < K) LOADF(aA,bA,ks+64);
    MFMAS(aB,bB);
  }
  int crow = (lane>>4)*4, ccol = lane&15;
  #pragma unroll
  for (int i=0;i<4;i++)
    #pragma unroll
    for (int j=0;j<4;j++)
      #pragma unroll
      for (int q=0;q<4;q++){
        int r = row0 + i*16 + crow + q;
        int c = col0 + j*16 + ccol;
        Cbf[(size_t)r*Nc + c] = f2b(acc[i][j][q]);
      }
}

// ---------------- edot2 ----------------
__global__ __launch_bounds__(256) void k_edot2(const unsigned short* __restrict__ h2bf, const float* __restrict__ a_src,
                        const float* __restrict__ a_dst, float* __restrict__ es, float* __restrict__ ed){
  int wave=threadIdx.x>>6, lane=threadIdx.x&63;
  int n = blockIdx.x*4+wave; if (n>=N_NODES) return;
  ushort2 hv = ((const ushort2*)(h2bf + (size_t)n*F2))[lane];
  float2 s2 = ((const float2*)a_src)[lane];
  float2 d2 = ((const float2*)a_dst)[lane];
  float h0=b2f(hv.x), h1=b2f(hv.y);
  float ps = h0*s2.x + h1*s2.y;
  float pd = h0*d2.x + h1*d2.y;
  #pragma unroll
  for (int m=1;m<64;m<<=1){ ps += __shfl_xor(ps,m); pd += __shfl_xor(pd,m); }
  if (lane==0){ es[n]=ps; ed[n]=pd; }
}

// ---------------- layer-1 aggregation: single-pass, degree-sorted ----------------
__global__ __launch_bounds__(256) void k_agg1(const unsigned short* __restrict__ h1bf, const float* __restrict__ es,
                       const float* __restrict__ ed, const int* __restrict__ offsets,
                       const int* __restrict__ ssrc, const int* __restrict__ perm,
                       const float* __restrict__ b1,
                       unsigned short* __restrict__ A2hi){
  int wave = threadIdx.x>>6, lane = threadIdx.x&63;
  int idx = blockIdx.x*4 + wave;
  if (idx >= M_PAD) return;
  if (idx >= N_NODES){
    ushort4 z = {0,0,0,0};
    ((ushort4*)(A2hi + (size_t)idx*F1))[lane] = z;
    return;
  }
  int d = perm[idx];
  int beg = offsets[d], end = offsets[d+1];
  int deg = end - beg;
  float4 edv = *(const float4*)(ed + (size_t)d*4);
  int head = lane>>4;
  float edh = head==0?edv.x:(head==1?edv.y:(head==2?edv.z:edv.w));
  float s0=0.f,s1=0.f,s2=0.f,s3=0.f;
  float4 acc0={0,0,0,0}, acc1={0,0,0,0}, acc2={0,0,0,0}, acc3={0,0,0,0};
  int j=0;
  for (; j+4<=deg; j+=4){
    int sn0=ssrc[beg+j], sn1=ssrc[beg+j+1], sn2=ssrc[beg+j+2], sn3=ssrc[beg+j+3];
    float e0 = es[(size_t)sn0*4+head], e1 = es[(size_t)sn1*4+head];
    float e2 = es[(size_t)sn2*4+head], e3 = es[(size_t)sn3*4+head];
    ushort4 v0 = ((const ushort4*)(h1bf + (size_t)sn0*F1))[lane];
    ushort4 v1 = ((const ushort4*)(h1bf + (size_t)sn1*F1))[lane];
    ushort4 v2 = ((const ushort4*)(h1bf + (size_t)sn2*F1))[lane];
    ushort4 v3 = ((const ushort4*)(h1bf + (size_t)sn3*F1))[lane];
    float x0 = __expf(leaky(e0+edh)), x1 = __expf(leaky(e1+edh));
    float x2 = __expf(leaky(e2+edh)), x3 = __expf(leaky(e3+edh));
    s0+=x0; s1+=x1; s2+=x2; s3+=x3;
    acc0.x=fmaf(x0,b2f(v0.x),acc0.x); acc0.y=fmaf(x0,b2f(v0.y),acc0.y); acc0.z=fmaf(x0,b2f(v0.z),acc0.z); acc0.w=fmaf(x0,b2f(v0.w),acc0.w);
    acc1.x=fmaf(x1,b2f(v1.x),acc1.x); acc1.y=fmaf(x1,b2f(v1.y),acc1.y); acc1.z=fmaf(x1,b2f(v1.z),acc1.z); acc1.w=fmaf(x1,b2f(v1.w),acc1.w);
    acc2.x=fmaf(x2,b2f(v2.x),acc2.x); acc2.y=fmaf(x2,b2f(v2.y),acc2.y); acc2.z=fmaf(x2,b2f(v2.z),acc2.z); acc2.w=fmaf(x2,b2f(v2.w),acc2.w);
    acc3.x=fmaf(x3,b2f(v3.x),acc3.x); acc3.y=fmaf(x3,b2f(v3.y),acc3.y); acc3.z=fmaf(x3,b2f(v3.z),acc3.z); acc3.w=fmaf(x3,b2f(v3.w),acc3.w);
  }
  for (; j<deg; j++){
    int sn=ssrc[beg+j];
    float e = es[(size_t)sn*4+head];
    ushort4 v = ((const ushort4*)(h1bf + (size_t)sn*F1))[lane];
    float x = __expf(leaky(e+edh));
    s0 += x;
    acc0.x=fmaf(x,b2f(v.x),acc0.x); acc0.y=fmaf(x,b2f(v.y),acc0.y);
    acc0.z=fmaf(x,b2f(v.z),acc0.z); acc0.w=fmaf(x,b2f(v.w),acc0.w);
  }
  float inv = 1.f/(s0+s1+s2+s3+1e-16f);
  float4 acc;
  acc.x = (acc0.x+acc1.x+acc2.x+acc3.x)*inv;
  acc.y = (acc0.y+acc1.y+acc2.y+acc3.y)*inv;
  acc.z = (acc0.z+acc1.z+acc2.z+acc3.z)*inv;
  acc.w = (acc0.w+acc1.w+acc2.w+acc3.w)*inv;
  float4 bb = *(const float4*)(b1 + lane*4);
  ushort4 hi;
  hi.x = f2b(elu_f(acc.x + bb.x));
  hi.y = f2b(elu_f(acc.y + bb.y));
  hi.z = f2b(elu_f(acc.z + bb.z));
  hi.w = f2b(elu_f(acc.w + bb.w));
  ((ushort4*)(A2hi + (size_t)d*F1))[lane] = hi;
}

// ---------------- layer-2 aggregation: single-pass + final mean ----------------
__global__ __launch_bounds__(256) void k_agg2(const unsigned short* __restrict__ h2bf, const float* __restrict__ es,
                       const float* __restrict__ ed, const int* __restrict__ offsets,
                       const int* __restrict__ ssrc, const int* __restrict__ perm,
                       const float* __restrict__ b2, float* __restrict__ out){
  int wave=threadIdx.x>>6, lane=threadIdx.x&63;
  int idx = blockIdx.x*4+wave; if (idx>=N_NODES) return;
  int d = perm[idx];
  int beg=offsets[d], end=offsets[d+1];
  int deg=end-beg;
  float edv = ed[d];
  float s0=0.f,s1=0.f,s2=0.f,s3=0.f;
  float2 acc0={0,0}, acc1={0,0}, acc2={0,0}, acc3={0,0};
  int j=0;
  for (; j+4<=deg; j+=4){
    int sn0=ssrc[beg+j], sn1=ssrc[beg+j+1], sn2=ssrc[beg+j+2], sn3=ssrc[beg+j+3];
    float e0=es[sn0], e1=es[sn1], e2=es[sn2], e3=es[sn3];
    ushort2 v0 = ((const ushort2*)(h2bf + (size_t)sn0*F2))[lane];
    ushort2 v1 = ((const ushort2*)(h2bf + (size_t)sn1*F2))[lane];
    ushort2 v2 = ((const ushort2*)(h2bf + (size_t)sn2*F2))[lane];
    ushort2 v3 = ((const ushort2*)(h2bf + (size_t)sn3*F2))[lane];
    float x0=__expf(leaky(e0+edv)), x1=__expf(leaky(e1+edv));
    float x2=__expf(leaky(e2+edv)), x3=__expf(leaky(e3+edv));
    s0+=x0; s1+=x1; s2+=x2; s3+=x3;
    acc0.x=fmaf(x0,b2f(v0.x),acc0.x); acc0.y=fmaf(x0,b2f(v0.y),acc0.y);
    acc1.x=fmaf(x1,b2f(v1.x),acc1.x); acc1.y=fmaf(x1,b2f(v1.y),acc1.y);
    acc2.x=fmaf(x2,b2f(v2.x),acc2.x); acc2.y=fmaf(x2,b2f(v2.y),acc2.y);
    acc3.x=fmaf(x3,b2f(v3.x),acc3.x); acc3.y=fmaf(x3,b2f(v3.y),acc3.y);
  }
  for (; j<deg; j++){
    int sn=ssrc[beg+j];
    float x = __expf(leaky(es[sn]+edv));
    ushort2 v = ((const ushort2*)(h2bf + (size_t)sn*F2))[lane];
    s0 += x;
    acc0.x=fmaf(x,b2f(v.x),acc0.x); acc0.y=fmaf(x,b2f(v.y),acc0.y);
  }
  float inv = 1.f/(s0+s1+s2+s3+1e-16f);
  float2 acc;
  acc.x = (acc0.x+acc1.x+acc2.x+acc3.x)*inv;
  acc.y = (acc0.y+acc1.y+acc2.y+acc3.y)*inv;
  float2 bb = *(const float2*)(b2 + lane*2);
  float r = elu_f(acc.x+bb.x) + elu_f(acc.y+bb.y);
  #pragma unroll
  for (int off=1;off<64;off<<=1) r += __shfl_xor(r,off);
  if (lane==0) out[d] = r * (1.f/128.f);
}

extern "C" void kernel_launch(void* const* d_in, const int* in_sizes, int n_in,
                              void* d_out, int out_size, void* d_ws, size_t ws_size,
                              hipStream_t stream) {
  const float* x   = (const float*)d_in[0];
  const int*   ei  = (const int*)d_in[1];
  const int*   esrc = ei;
  const int*   edst = ei + N_EDGES;
  const float* W1  = (const float*)d_in[2];
  const float* a1s = (const float*)d_in[3];
  const float* a1d = (const float*)d_in[4];
  const float* b1  = (const float*)d_in[5];
  const float* W2  = (const float*)d_in[6];
  const float* a2s = (const float*)d_in[7];
  const float* a2d = (const float*)d_in[8];
  const float* b2  = (const float*)d_in[9];
  float* out = (float*)d_out;

  char* ws = (char*)d_ws;
  size_t off = 0;
  auto alloc = [&](size_t bytes)->void*{ void* p = ws + off; off += (bytes + 255) & ~(size_t)255; return p; };
  unsigned short* A1hi = (unsigned short*)alloc((size_t)M_PAD*F1*2);
  unsigned short* h1bf = (unsigned short*)alloc((size_t)M_PAD*F1*2);
  unsigned short* h2bf = (unsigned short*)alloc((size_t)M_PAD*F2*2);
  unsigned short* Bt1hi= (unsigned short*)alloc((size_t)F1*DIN*2);
  unsigned short* Bt2hi= (unsigned short*)alloc((size_t)F2*F1*2);
  float* e1s   = (float*)alloc((size_t)M_PAD*HEADS*4);
  float* e1d   = (float*)alloc((size_t)M_PAD*HEADS*4);
  float* e2s   = (float*)alloc((size_t)N_NODES*4);
  float* e2d   = (float*)alloc((size_t)N_NODES*4);
  int*   counts= (int*)alloc((size_t)N_NODES*4);
  int*   offs  = (int*)alloc((size_t)(N_NODES+1)*4);
  int*   cursor= (int*)alloc((size_t)N_NODES*4);
  int*   exc   = (int*)alloc((size_t)N_NODES*4);
  int*   bsum  = (int*)alloc((size_t)SCAN_NBLK*4);
  int*   bpref = (int*)alloc((size_t)SCAN_NBLK*4);
  int*   perm  = (int*)alloc((size_t)N_NODES*4);
  int*   dbin  = (int*)alloc((size_t)256*4);
  int*   dbase = (int*)alloc((size_t)256*4);
  int*   bcount= (int*)alloc((size_t)SCAN_NBLK*256*4);
  int*   colbase=(int*)alloc((size_t)SCAN_NBLK*256*4);
  int*   ssrc  = (int*)alloc((size_t)EP*4);
  unsigned short* A2hi = A1hi;   // layer-1 input dead after gemm1

  hipMemsetAsync(counts, 0, (size_t)N_NODES*4, stream);
  hipMemsetAsync(dbin, 0, (size_t)256*4, stream);
  k_hist<<<(EP+255)/256, 256, 0, stream>>>(edst, counts);
  k_scan1<<<SCAN_NBLK, 256, 0, stream>>>(counts, exc, bsum);
  k_scan2<<<1, 256, 0, stream>>>(bsum, bpref, offs);
  k_scan3<<<SCAN_NBLK, 256, 0, stream>>>(exc, bpref, offs, cursor);
  k_scatter<<<(EP+255)/256, 256, 0, stream>>>(esrc, edst, cursor, ssrc);
  k_dhist<<<SCAN_NBLK, 256, 0, stream>>>(counts, dbin, bcount);
  k_dscan<<<1, 256, 0, stream>>>(dbin, dbase);
  k_dcol<<<1, 256, 0, stream>>>(bcount, dbase, colbase);
  k_dscatter<<<SCAN_NBLK, 256, 0, stream>>>(counts, colbase, perm);

  k_splitA<<<(M_PAD*F1/4 + 255)/256, 256, 0, stream>>>(x, A1hi);
  k_splitWT<<<(DIN*F1 + 255)/256, 256, 0, stream>>>(W1, Bt1hi, DIN, F1);
  k_splitWT<<<(F1*F2 + 255)/256, 256, 0, stream>>>(W2, Bt2hi, F1, F2);

  k_gemm1f<<<M_PAD/64, 256, 0, stream>>>(A1hi, Bt1hi, a1s, a1d, h1bf, e1s, e1d);
  k_agg1<<<(M_PAD+3)/4, 256, 0, stream>>>(h1bf, e1s, e1d, offs, ssrc, perm, b1, A2hi);

  k_gemm_bf<2,2><<<M_PAD/128, 256, 0, stream>>>(A2hi, Bt2hi, h2bf, F2);
  k_edot2<<<(N_NODES+3)/4, 256, 0, stream>>>(h2bf, a2s, a2d, e2s, e2d);
  k_agg2<<<(N_NODES+3)/4, 256, 0, stream>>>(h2bf, e2s, e2d, offs, ssrc, perm, b2, out);
}

// Round 9
// 322.981 us; speedup vs baseline: 1.9574x; 1.0193x over previous
//
#include <hip/hip_runtime.h>
#include <math.h>

#define N_NODES 50000
#define M_PAD   50048            /* 391*128 = 782*64 */
#define N_EDGES 800000
#define EP (N_EDGES + N_NODES)
#define DIN 256
#define HEADS 4
#define HID 64
#define F1 256
#define F2 128
#define NEG_SLOPE 0.2f
#define SCAN_NBLK ((N_NODES + 255)/256)   /* 196 */

typedef short bf16x8 __attribute__((ext_vector_type(8)));
typedef float f32x4  __attribute__((ext_vector_type(4)));

static __device__ __forceinline__ float leaky(float x){ return x > 0.f ? x : NEG_SLOPE*x; }
static __device__ __forceinline__ float elu_f(float x){ return x > 0.f ? x : (__expf(x)-1.f); }
static __device__ __forceinline__ float b2f(unsigned short u){ return __uint_as_float(((unsigned)u)<<16); }
static __device__ __forceinline__ unsigned short f2b(float f){
  unsigned u = __float_as_uint(f);
  return (unsigned short)((u + 0x7fffu + ((u>>16)&1u)) >> 16);   // RNE
}

// ---------------- CSR build ----------------
__global__ __launch_bounds__(256) void k_hist(const int* __restrict__ dst, int* __restrict__ counts){
  int e = blockIdx.x*256 + threadIdx.x;
  if (e >= EP) return;
  int d = (e < N_EDGES) ? dst[e] : (e - N_EDGES);
  atomicAdd(&counts[d], 1);
}

__global__ __launch_bounds__(256) void k_scan1(const int* __restrict__ counts,
                                               int* __restrict__ exc, int* __restrict__ bsum){
  int i = blockIdx.x*256 + threadIdx.x;
  int v = (i < N_NODES) ? counts[i] : 0;
  int lane = threadIdx.x & 63, wave = threadIdx.x >> 6;
  int inc = v;
  #pragma unroll
  for (int off=1; off<64; off<<=1){
    int n = __shfl_up(inc, off);
    if (lane >= off) inc += n;
  }
  __shared__ int wsum[4];
  if (lane == 63) wsum[wave] = inc;
  __syncthreads();
  int wpre = 0;
  #pragma unroll
  for (int w=0; w<4; w++) if (w < wave) wpre += wsum[w];
  if (i < N_NODES) exc[i] = wpre + inc - v;
  if (threadIdx.x == 255) bsum[blockIdx.x] = wpre + inc;
}

__global__ __launch_bounds__(256) void k_scan2(const int* __restrict__ bsum,
                                               int* __restrict__ bpref, int* __restrict__ offsets){
  int i = threadIdx.x;
  int v = (i < SCAN_NBLK) ? bsum[i] : 0;
  int lane = threadIdx.x & 63, wave = threadIdx.x >> 6;
  int inc = v;
  #pragma unroll
  for (int off=1; off<64; off<<=1){
    int n = __shfl_up(inc, off);
    if (lane >= off) inc += n;
  }
  __shared__ int wsum[4];
  if (lane == 63) wsum[wave] = inc;
  __syncthreads();
  int wpre = 0;
  #pragma unroll
  for (int w=0; w<4; w++) if (w < wave) wpre += wsum[w];
  if (i < SCAN_NBLK) bpref[i] = wpre + inc - v;
  if (i == 255) offsets[N_NODES] = wpre + inc;
}

__global__ __launch_bounds__(256) void k_scan3(const int* __restrict__ exc, const int* __restrict__ bpref,
                                               int* __restrict__ offsets, int* __restrict__ cursor){
  int i = blockIdx.x*256 + threadIdx.x;
  if (i >= N_NODES) return;
  int o = exc[i] + bpref[blockIdx.x];
  offsets[i] = o;
  cursor[i] = o;
}

__global__ __launch_bounds__(256) void k_scatter(const int* __restrict__ src, const int* __restrict__ dst,
                          int* __restrict__ cursor, int* __restrict__ sorted_src, int* __restrict__ sorted_dst){
  int e = blockIdx.x*256 + threadIdx.x;
  if (e >= EP) return;
  int s, d;
  if (e < N_EDGES){ s = src[e]; d = dst[e]; } else { s = d = e - N_EDGES; }
  int pos = atomicAdd(&cursor[d], 1);
  sorted_src[pos] = s;
  sorted_dst[pos] = d;
}

// ---------------- contention-free degree counting sort ----------------
__global__ __launch_bounds__(256) void k_dhist(const int* __restrict__ counts,
                                               int* __restrict__ dbin, int* __restrict__ bcount){
  __shared__ int h[256];
  h[threadIdx.x] = 0;
  __syncthreads();
  int i = blockIdx.x*256 + threadIdx.x;
  if (i < N_NODES){
    int b = counts[i]; if (b > 255) b = 255;
    atomicAdd(&h[b], 1);
  }
  __syncthreads();
  int c = h[threadIdx.x];
  bcount[(size_t)blockIdx.x*256 + threadIdx.x] = c;
  if (c) atomicAdd(&dbin[threadIdx.x], c);
}

__global__ __launch_bounds__(256) void k_dscan(const int* __restrict__ dbin, int* __restrict__ dbase){
  int i = threadIdx.x;
  int v = dbin[i];
  int lane = threadIdx.x & 63, wave = threadIdx.x >> 6;
  int inc = v;
  #pragma unroll
  for (int off=1; off<64; off<<=1){
    int n = __shfl_up(inc, off);
    if (lane >= off) inc += n;
  }
  __shared__ int wsum[4];
  if (lane == 63) wsum[wave] = inc;
  __syncthreads();
  int wpre = 0;
  #pragma unroll
  for (int w=0; w<4; w++) if (w < wave) wpre += wsum[w];
  dbase[i] = wpre + inc - v;
}

__global__ __launch_bounds__(256) void k_dcol(const int* __restrict__ bcount, const int* __restrict__ dbase,
                                              int* __restrict__ colbase){
  int bin = threadIdx.x;
  int run = dbase[bin];
  for (int blk=0; blk<SCAN_NBLK; blk++){
    colbase[(size_t)blk*256 + bin] = run;
    run += bcount[(size_t)blk*256 + bin];
  }
}

__global__ __launch_bounds__(256) void k_dscatter(const int* __restrict__ counts, const int* __restrict__ colbase,
                                                  int* __restrict__ perm){
  __shared__ int h[256];
  h[threadIdx.x] = 0;
  __syncthreads();
  int i = blockIdx.x*256 + threadIdx.x;
  if (i < N_NODES){
    int b = counts[i]; if (b > 255) b = 255;
    int r = atomicAdd(&h[b], 1);
    perm[colbase[(size_t)blockIdx.x*256 + b] + r] = i;
  }
}

// ---------------- f32 -> bf16 (padded rows zeroed) ----------------
__global__ __launch_bounds__(256) void k_splitA(const float* __restrict__ X,
                         unsigned short* __restrict__ Ahi){
  int gid = blockIdx.x*256 + threadIdx.x;
  size_t base = (size_t)gid*4;
  int row = (int)(base >> 8);
  ushort4 hi;
  if (row < N_NODES){
    float4 v = *(const float4*)(X + base);
    hi.x=f2b(v.x); hi.y=f2b(v.y); hi.z=f2b(v.z); hi.w=f2b(v.w);
  } else {
    hi = {0,0,0,0};
  }
  *(ushort4*)(Ahi + base) = hi;
}

__global__ __launch_bounds__(256) void k_splitWT(const float* __restrict__ W,
                          unsigned short* __restrict__ Bhi, int Kd, int Nd){
  int t = blockIdx.x*256 + threadIdx.x;
  if (t >= Kd*Nd) return;
  int n = t / Kd, k = t % Kd;
  Bhi[(size_t)n*Kd + k] = f2b(W[(size_t)k*Nd + n]);
}

// ---------------- GEMM1 bf16 (WR=1, WC=4) + fused edot1, 2-stage prefetch ----------------
__global__ __launch_bounds__(256) void k_gemm1f(
    const unsigned short* __restrict__ A, const unsigned short* __restrict__ Bt,
    const float* __restrict__ a1s, const float* __restrict__ a1d,
    unsigned short* __restrict__ Cbf, float* __restrict__ es, float* __restrict__ ed){
  const int K = 256, Nc = F1;
  int tid = threadIdx.x;
  int wave = tid>>6, lane = tid&63;
  int wc = wave;                 // head
  int row0 = blockIdx.x*64;
  int col0 = wc*64;
  int lrow = lane&15, lk = (lane>>4)*8;
  f32x4 acc[4][4] = {};
  bf16x8 aA[4], bA[4], aB[4], bB[4];
  auto LOADF = [&](bf16x8* av, bf16x8* bv, int KS){
    #pragma unroll
    for (int i=0;i<4;i++){
      av[i] = *(const bf16x8*)(A  + (unsigned)(row0 + i*16 + lrow)*K + KS + lk);
      bv[i] = *(const bf16x8*)(Bt + (unsigned)(col0 + i*16 + lrow)*K + KS + lk);
    }
  };
  auto MFMAS = [&](bf16x8* av, bf16x8* bv){
    #pragma unroll
    for (int i=0;i<4;i++)
      #pragma unroll
      for (int j=0;j<4;j++)
        acc[i][j] = __builtin_amdgcn_mfma_f32_16x16x32_bf16(av[i], bv[j], acc[i][j], 0,0,0);
  };
  LOADF(aA,bA,0);
  #pragma unroll
  for (int ks=0; ks<K; ks+=64){
    LOADF(aB,bB,ks+32);
    MFMAS(aA,bA);
    if (ks+64 < K) LOADF(aA,bA,ks+64);
    MFMAS(aB,bB);
  }
  int crow = (lane>>4)*4, ccol = lane&15;
  #pragma unroll
  for (int i=0;i<4;i++)
    #pragma unroll
    for (int j=0;j<4;j++)
      #pragma unroll
      for (int q=0;q<4;q++){
        int r = row0 + i*16 + crow + q;
        int c = col0 + j*16 + ccol;
        Cbf[(unsigned)r*Nc + c] = f2b(acc[i][j][q]);
      }
  float avs[4], avd[4];
  #pragma unroll
  for (int j=0;j<4;j++){
    avs[j] = a1s[wc*64 + j*16 + ccol];
    avd[j] = a1d[wc*64 + j*16 + ccol];
  }
  #pragma unroll
  for (int i=0;i<4;i++){
    #pragma unroll
    for (int q=0;q<4;q++){
      float ps = acc[i][0][q]*avs[0] + acc[i][1][q]*avs[1] + acc[i][2][q]*avs[2] + acc[i][3][q]*avs[3];
      float pd = acc[i][0][q]*avd[0] + acc[i][1][q]*avd[1] + acc[i][2][q]*avd[2] + acc[i][3][q]*avd[3];
      #pragma unroll
      for (int off=1; off<16; off<<=1){ ps += __shfl_xor(ps,off); pd += __shfl_xor(pd,off); }
      if ((lane&15)==0){
        int r = row0 + i*16 + crow + q;
        es[(unsigned)r*4 + wc] = ps;
        ed[(unsigned)r*4 + wc] = pd;
      }
    }
  }
}

// ---------------- plain bf16 GEMM (layer 2), 2-stage prefetch ----------------
template<int WR, int WC>
__global__ __launch_bounds__(256) void k_gemm_bf(
    const unsigned short* __restrict__ A, const unsigned short* __restrict__ Bt,
    unsigned short* __restrict__ Cbf, int Nc){
  const int K = 256;
  int tid = threadIdx.x;
  int wave = tid>>6, lane = tid&63;
  int wr = wave / WC, wc = wave % WC;
  int row0 = blockIdx.x*(WR*64) + wr*64;
  int col0 = blockIdx.y*(WC*64) + wc*64;
  int lrow = lane&15, lk = (lane>>4)*8;
  f32x4 acc[4][4] = {};
  bf16x8 aA[4], bA[4], aB[4], bB[4];
  auto LOADF = [&](bf16x8* av, bf16x8* bv, int KS){
    #pragma unroll
    for (int i=0;i<4;i++){
      av[i] = *(const bf16x8*)(A  + (unsigned)(row0 + i*16 + lrow)*K + KS + lk);
      bv[i] = *(const bf16x8*)(Bt + (unsigned)(col0 + i*16 + lrow)*K + KS + lk);
    }
  };
  auto MFMAS = [&](bf16x8* av, bf16x8* bv){
    #pragma unroll
    for (int i=0;i<4;i++)
      #pragma unroll
      for (int j=0;j<4;j++)
        acc[i][j] = __builtin_amdgcn_mfma_f32_16x16x32_bf16(av[i], bv[j], acc[i][j], 0,0,0);
  };
  LOADF(aA,bA,0);
  #pragma unroll
  for (int ks=0; ks<K; ks+=64){
    LOADF(aB,bB,ks+32);
    MFMAS(aA,bA);
    if (ks+64 < K) LOADF(aA,bA,ks+64);
    MFMAS(aB,bB);
  }
  int crow = (lane>>4)*4, ccol = lane&15;
  #pragma unroll
  for (int i=0;i<4;i++)
    #pragma unroll
    for (int j=0;j<4;j++)
      #pragma unroll
      for (int q=0;q<4;q++){
        int r = row0 + i*16 + crow + q;
        int c = col0 + j*16 + ccol;
        Cbf[(unsigned)r*Nc + c] = f2b(acc[i][j][q]);
      }
}

// ---------------- edot2 ----------------
__global__ __launch_bounds__(256) void k_edot2(const unsigned short* __restrict__ h2bf, const float* __restrict__ a_src,
                        const float* __restrict__ a_dst, float* __restrict__ es, float* __restrict__ ed){
  int wave=threadIdx.x>>6, lane=threadIdx.x&63;
  int n = blockIdx.x*4+wave; if (n>=N_NODES) return;
  ushort2 hv = ((const ushort2*)(h2bf + (unsigned)n*F2))[lane];
  float2 s2 = ((const float2*)a_src)[lane];
  float2 d2 = ((const float2*)a_dst)[lane];
  float h0=b2f(hv.x), h1=b2f(hv.y);
  float ps = h0*s2.x + h1*s2.y;
  float pd = h0*d2.x + h1*d2.y;
  #pragma unroll
  for (int m=1;m<64;m<<=1){ ps += __shfl_xor(ps,m); pd += __shfl_xor(pd,m); }
  if (lane==0){ es[n]=ps; ed[n]=pd; }
}

// ---------------- per-edge exp pre-passes ----------------
__global__ __launch_bounds__(256) void k_eexp1(const int* __restrict__ ssrc, const int* __restrict__ sdst,
                        const float* __restrict__ es, const float* __restrict__ ed,
                        float* __restrict__ ex){
  int e = blockIdx.x*256 + threadIdx.x;
  if (e >= EP) return;
  unsigned s = (unsigned)ssrc[e], d = (unsigned)sdst[e];
  float4 ev = *(const float4*)(es + s*4);
  float4 dv = *(const float4*)(ed + d*4);
  float4 o;
  o.x = __expf(leaky(ev.x+dv.x));
  o.y = __expf(leaky(ev.y+dv.y));
  o.z = __expf(leaky(ev.z+dv.z));
  o.w = __expf(leaky(ev.w+dv.w));
  *(float4*)(ex + (unsigned)e*4) = o;
}

__global__ __launch_bounds__(256) void k_eexp2(const int* __restrict__ ssrc, const int* __restrict__ sdst,
                        const float* __restrict__ es, const float* __restrict__ ed,
                        float* __restrict__ ex){
  int e = blockIdx.x*256 + threadIdx.x;
  if (e >= EP) return;
  unsigned s = (unsigned)ssrc[e], d = (unsigned)sdst[e];
  ex[e] = __expf(leaky(es[s] + ed[d]));
}

// ---------------- layer-1 aggregation: precomputed ex, 32-bit addressing ----------------
__global__ __launch_bounds__(256) void k_agg1(const unsigned short* __restrict__ h1bf, const float* __restrict__ ex1,
                       const int* __restrict__ offsets,
                       const int* __restrict__ ssrc, const int* __restrict__ perm,
                       const float* __restrict__ b1,
                       unsigned short* __restrict__ A2hi){
  int wave = threadIdx.x>>6, lane = threadIdx.x&63;
  int idx = blockIdx.x*4 + wave;
  if (idx >= M_PAD) return;
  if (idx >= N_NODES){
    ushort4 z = {0,0,0,0};
    ((ushort4*)(A2hi + (unsigned)idx*F1))[lane] = z;
    return;
  }
  int d = perm[idx];
  unsigned beg = (unsigned)offsets[d], end = (unsigned)offsets[d+1];
  unsigned deg = end - beg;
  unsigned head = (unsigned)(lane>>4);
  const ushort4* __restrict__ hb = (const ushort4*)h1bf;   // row stride 64 ushort4
  const float* __restrict__ exh = ex1 + head;              // ex1[e*4+head]
  float s0=0.f,s1=0.f,s2=0.f,s3=0.f;
  float4 acc0={0,0,0,0}, acc1={0,0,0,0}, acc2={0,0,0,0}, acc3={0,0,0,0};
  unsigned j=0;
  for (; j+4<=deg; j+=4){
    unsigned e0=beg+j;
    unsigned sn0=(unsigned)ssrc[e0], sn1=(unsigned)ssrc[e0+1], sn2=(unsigned)ssrc[e0+2], sn3=(unsigned)ssrc[e0+3];
    float x0 = exh[e0*4], x1 = exh[e0*4+4], x2 = exh[e0*4+8], x3 = exh[e0*4+12];
    ushort4 v0 = hb[sn0*64 + lane];
    ushort4 v1 = hb[sn1*64 + lane];
    ushort4 v2 = hb[sn2*64 + lane];
    ushort4 v3 = hb[sn3*64 + lane];
    s0+=x0; s1+=x1; s2+=x2; s3+=x3;
    acc0.x=fmaf(x0,b2f(v0.x),acc0.x); acc0.y=fmaf(x0,b2f(v0.y),acc0.y); acc0.z=fmaf(x0,b2f(v0.z),acc0.z); acc0.w=fmaf(x0,b2f(v0.w),acc0.w);
    acc1.x=fmaf(x1,b2f(v1.x),acc1.x); acc1.y=fmaf(x1,b2f(v1.y),acc1.y); acc1.z=fmaf(x1,b2f(v1.z),acc1.z); acc1.w=fmaf(x1,b2f(v1.w),acc1.w);
    acc2.x=fmaf(x2,b2f(v2.x),acc2.x); acc2.y=fmaf(x2,b2f(v2.y),acc2.y); acc2.z=fmaf(x2,b2f(v2.z),acc2.z); acc2.w=fmaf(x2,b2f(v2.w),acc2.w);
    acc3.x=fmaf(x3,b2f(v3.x),acc3.x); acc3.y=fmaf(x3,b2f(v3.y),acc3.y); acc3.z=fmaf(x3,b2f(v3.z),acc3.z); acc3.w=fmaf(x3,b2f(v3.w),acc3.w);
  }
  for (; j<deg; j++){
    unsigned e0=beg+j;
    unsigned sn=(unsigned)ssrc[e0];
    float x = exh[e0*4];
    ushort4 v = hb[sn*64 + lane];
    s0 += x;
    acc0.x=fmaf(x,b2f(v.x),acc0.x); acc0.y=fmaf(x,b2f(v.y),acc0.y);
    acc0.z=fmaf(x,b2f(v.z),acc0.z); acc0.w=fmaf(x,b2f(v.w),acc0.w);
  }
  float inv = 1.f/(s0+s1+s2+s3+1e-16f);
  float4 acc;
  acc.x = (acc0.x+acc1.x+acc2.x+acc3.x)*inv;
  acc.y = (acc0.y+acc1.y+acc2.y+acc3.y)*inv;
  acc.z = (acc0.z+acc1.z+acc2.z+acc3.z)*inv;
  acc.w = (acc0.w+acc1.w+acc2.w+acc3.w)*inv;
  float4 bb = *(const float4*)(b1 + lane*4);
  ushort4 hi;
  hi.x = f2b(elu_f(acc.x + bb.x));
  hi.y = f2b(elu_f(acc.y + bb.y));
  hi.z = f2b(elu_f(acc.z + bb.z));
  hi.w = f2b(elu_f(acc.w + bb.w));
  ((ushort4*)(A2hi + (unsigned)d*F1))[lane] = hi;
}

// ---------------- layer-2 aggregation: precomputed ex + final mean ----------------
__global__ __launch_bounds__(256) void k_agg2(const unsigned short* __restrict__ h2bf, const float* __restrict__ ex2,
                       const int* __restrict__ offsets,
                       const int* __restrict__ ssrc, const int* __restrict__ perm,
                       const float* __restrict__ b2, float* __restrict__ out){
  int wave=threadIdx.x>>6, lane=threadIdx.x&63;
  int idx = blockIdx.x*4+wave; if (idx>=N_NODES) return;
  int d = perm[idx];
  unsigned beg=(unsigned)offsets[d], end=(unsigned)offsets[d+1];
  unsigned deg=end-beg;
  const ushort2* __restrict__ hb = (const ushort2*)h2bf;   // row stride 64 ushort2
  float s0=0.f,s1=0.f,s2=0.f,s3=0.f;
  float2 acc0={0,0}, acc1={0,0}, acc2={0,0}, acc3={0,0};
  unsigned j=0;
  for (; j+4<=deg; j+=4){
    unsigned e0=beg+j;
    unsigned sn0=(unsigned)ssrc[e0], sn1=(unsigned)ssrc[e0+1], sn2=(unsigned)ssrc[e0+2], sn3=(unsigned)ssrc[e0+3];
    float x0=ex2[e0], x1=ex2[e0+1], x2=ex2[e0+2], x3=ex2[e0+3];
    ushort2 v0 = hb[sn0*64 + lane];
    ushort2 v1 = hb[sn1*64 + lane];
    ushort2 v2 = hb[sn2*64 + lane];
    ushort2 v3 = hb[sn3*64 + lane];
    s0+=x0; s1+=x1; s2+=x2; s3+=x3;
    acc0.x=fmaf(x0,b2f(v0.x),acc0.x); acc0.y=fmaf(x0,b2f(v0.y),acc0.y);
    acc1.x=fmaf(x1,b2f(v1.x),acc1.x); acc1.y=fmaf(x1,b2f(v1.y),acc1.y);
    acc2.x=fmaf(x2,b2f(v2.x),acc2.x); acc2.y=fmaf(x2,b2f(v2.y),acc2.y);
    acc3.x=fmaf(x3,b2f(v3.x),acc3.x); acc3.y=fmaf(x3,b2f(v3.y),acc3.y);
  }
  for (; j<deg; j++){
    unsigned e0=beg+j;
    unsigned sn=(unsigned)ssrc[e0];
    float x = ex2[e0];
    ushort2 v = hb[sn*64 + lane];
    s0 += x;
    acc0.x=fmaf(x,b2f(v.x),acc0.x); acc0.y=fmaf(x,b2f(v.y),acc0.y);
  }
  float inv = 1.f/(s0+s1+s2+s3+1e-16f);
  float2 acc;
  acc.x = (acc0.x+acc1.x+acc2.x+acc3.x)*inv;
  acc.y = (acc0.y+acc1.y+acc2.y+acc3.y)*inv;
  float2 bb = *(const float2*)(b2 + lane*2);
  float r = elu_f(acc.x+bb.x) + elu_f(acc.y+bb.y);
  #pragma unroll
  for (int off=1;off<64;off<<=1) r += __shfl_xor(r,off);
  if (lane==0) out[d] = r * (1.f/128.f);
}

extern "C" void kernel_launch(void* const* d_in, const int* in_sizes, int n_in,
                              void* d_out, int out_size, void* d_ws, size_t ws_size,
                              hipStream_t stream) {
  const float* x   = (const float*)d_in[0];
  const int*   ei  = (const int*)d_in[1];
  const int*   esrc = ei;
  const int*   edst = ei + N_EDGES;
  const float* W1  = (const float*)d_in[2];
  const float* a1s = (const float*)d_in[3];
  const float* a1d = (const float*)d_in[4];
  const float* b1  = (const float*)d_in[5];
  const float* W2  = (const float*)d_in[6];
  const float* a2s = (const float*)d_in[7];
  const float* a2d = (const float*)d_in[8];
  const float* b2  = (const float*)d_in[9];
  float* out = (float*)d_out;

  char* ws = (char*)d_ws;
  size_t off = 0;
  auto alloc = [&](size_t bytes)->void*{ void* p = ws + off; off += (bytes + 255) & ~(size_t)255; return p; };
  unsigned short* A1hi = (unsigned short*)alloc((size_t)M_PAD*F1*2);
  unsigned short* h1bf = (unsigned short*)alloc((size_t)M_PAD*F1*2);
  unsigned short* h2bf = (unsigned short*)alloc((size_t)M_PAD*F2*2);
  unsigned short* Bt1hi= (unsigned short*)alloc((size_t)F1*DIN*2);
  unsigned short* Bt2hi= (unsigned short*)alloc((size_t)F2*F1*2);
  float* e1s   = (float*)alloc((size_t)M_PAD*HEADS*4);
  float* e1d   = (float*)alloc((size_t)M_PAD*HEADS*4);
  float* e2s   = (float*)alloc((size_t)N_NODES*4);
  float* e2d   = (float*)alloc((size_t)N_NODES*4);
  float* ex1   = (float*)alloc((size_t)EP*HEADS*4);
  float* ex2   = (float*)alloc((size_t)EP*4);
  int*   counts= (int*)alloc((size_t)N_NODES*4);
  int*   offs  = (int*)alloc((size_t)(N_NODES+1)*4);
  int*   cursor= (int*)alloc((size_t)N_NODES*4);
  int*   exc   = (int*)alloc((size_t)N_NODES*4);
  int*   bsum  = (int*)alloc((size_t)SCAN_NBLK*4);
  int*   bpref = (int*)alloc((size_t)SCAN_NBLK*4);
  int*   perm  = (int*)alloc((size_t)N_NODES*4);
  int*   dbin  = (int*)alloc((size_t)256*4);
  int*   dbase = (int*)alloc((size_t)256*4);
  int*   bcount= (int*)alloc((size_t)SCAN_NBLK*256*4);
  int*   colbase=(int*)alloc((size_t)SCAN_NBLK*256*4);
  int*   ssrc  = (int*)alloc((size_t)EP*4);
  int*   sdst  = (int*)alloc((size_t)EP*4);
  unsigned short* A2hi = A1hi;   // layer-1 input dead after gemm1

  hipMemsetAsync(counts, 0, (size_t)N_NODES*4, stream);
  hipMemsetAsync(dbin, 0, (size_t)256*4, stream);
  k_hist<<<(EP+255)/256, 256, 0, stream>>>(edst, counts);
  k_scan1<<<SCAN_NBLK, 256, 0, stream>>>(counts, exc, bsum);
  k_scan2<<<1, 256, 0, stream>>>(bsum, bpref, offs);
  k_scan3<<<SCAN_NBLK, 256, 0, stream>>>(exc, bpref, offs, cursor);
  k_scatter<<<(EP+255)/256, 256, 0, stream>>>(esrc, edst, cursor, ssrc, sdst);
  k_dhist<<<SCAN_NBLK, 256, 0, stream>>>(counts, dbin, bcount);
  k_dscan<<<1, 256, 0, stream>>>(dbin, dbase);
  k_dcol<<<1, 256, 0, stream>>>(bcount, dbase, colbase);
  k_dscatter<<<SCAN_NBLK, 256, 0, stream>>>(counts, colbase, perm);

  k_splitA<<<(M_PAD*F1/4 + 255)/256, 256, 0, stream>>>(x, A1hi);
  k_splitWT<<<(DIN*F1 + 255)/256, 256, 0, stream>>>(W1, Bt1hi, DIN, F1);
  k_splitWT<<<(F1*F2 + 255)/256, 256, 0, stream>>>(W2, Bt2hi, F1, F2);

  k_gemm1f<<<M_PAD/64, 256, 0, stream>>>(A1hi, Bt1hi, a1s, a1d, h1bf, e1s, e1d);
  k_eexp1<<<(EP+255)/256, 256, 0, stream>>>(ssrc, sdst, e1s, e1d, ex1);
  k_agg1<<<(M_PAD+3)/4, 256, 0, stream>>>(h1bf, ex1, offs, ssrc, perm, b1, A2hi);

  k_gemm_bf<2,2><<<M_PAD/128, 256, 0, stream>>>(A2hi, Bt2hi, h2bf, F2);
  k_edot2<<<(N_NODES+3)/4, 256, 0, stream>>>(h2bf, a2s, a2d, e2s, e2d);
  k_eexp2<<<(EP+255)/256, 256, 0, stream>>>(ssrc, sdst, e2s, e2d, ex2);
  k_agg2<<<(N_NODES+3)/4, 256, 0, stream>>>(h2bf, ex2, offs, ssrc, perm, b2, out);
}